// Round 3
// baseline (5269.963 us; speedup 1.0000x reference)
//
#include <hip/hip_runtime.h>
#include <hip/hip_bf16.h>

// ---------------------------------------------------------------------------
// ROLAND GNN forward. Device buffers are FLOAT32 (per reference dtypes);
// matmuls run bf16-MFMA internally with f32 accumulation.
// Outputs (concat, f32): logits[EL], emb0[N,128], emb1[N,128], emb2[N,128]
// Buffer plan:
//   ws: dinv f32[N] | bf16 weight copies (590KB) | agg f32[N*cw] (conv2)
//   H1 [N,256] staged across emb1+emb2 slots; conv xw staged in emb2 slot;
//   conv1 agg lives in the dead emb1 slot (finalize in place).
// ---------------------------------------------------------------------------

typedef __bf16 bf16;
typedef __bf16 bf16x8 __attribute__((ext_vector_type(8)));
typedef float  f32x4  __attribute__((ext_vector_type(4)));

#define DEV __device__ __forceinline__

DEV f32x4 mfma16(bf16x8 a, bf16x8 b, f32x4 c) {
    return __builtin_amdgcn_mfma_f32_16x16x32_bf16(a, b, c, 0, 0, 0);
}

// load 8 consecutive f32 and round to bf16x8 (RNE via cast)
DEV bf16x8 load8_cvt(const float* p) {
    f32x4 lo = *(const f32x4*)p;
    f32x4 hi = *(const f32x4*)(p + 4);
    bf16x8 v;
    v[0] = (bf16)lo[0]; v[1] = (bf16)lo[1]; v[2] = (bf16)lo[2]; v[3] = (bf16)lo[3];
    v[4] = (bf16)hi[0]; v[5] = (bf16)hi[1]; v[6] = (bf16)hi[2]; v[7] = (bf16)hi[3];
    return v;
}

// f32 -> bf16 weight pre-conversion
__global__ void cvt_kernel(const float* __restrict__ in, bf16* __restrict__ ob, int n) {
    const int i = blockIdx.x * 256 + threadIdx.x;
    if (i < n) ob[i] = (bf16)in[i];
}

// ---------------------------------------------------------------------------
// GEMM: C[M,Co] = act(A[M,Ci] @ W[Co,Ci]^T + bias). A f32, W bf16 (pre-cvt).
// block = 256 (4 waves); wave w owns rows [blk*64 + w*16, +16).
// MFMA 16x16x32 bf16; C/D layout (m89): col=lane&15, row=4*(lane>>4)+j.
// ---------------------------------------------------------------------------
template<int Ci, int Co, bool ACT, bool BIAS>
__global__ __launch_bounds__(256) void gemm_kernel(
    const float* __restrict__ A, const bf16* __restrict__ W,
    const float* __restrict__ bias, float* __restrict__ C, int M)
{
    const int tid  = threadIdx.x;
    const int lane = tid & 63, w = tid >> 6;
    const int lr   = lane & 15, ko = lane >> 4;
    const int rbase = blockIdx.x * 64 + w * 16;

    long arow = rbase + lr; if (arow > M - 1) arow = M - 1;  // clamped rows never stored
    constexpr int KC = Ci / 32;
    constexpr int NT = Co / 16;

    bf16x8 a[KC];
#pragma unroll
    for (int kc = 0; kc < KC; ++kc)
        a[kc] = load8_cvt(A + arow * Ci + kc * 32 + ko * 8);

#pragma unroll
    for (int t = 0; t < NT; ++t) {
        f32x4 acc = {0.f, 0.f, 0.f, 0.f};
        const bf16* wp = W + (long)(t * 16 + lr) * Ci + ko * 8;
#pragma unroll
        for (int kc = 0; kc < KC; ++kc)
            acc = mfma16(a[kc], *(const bf16x8*)(wp + kc * 32), acc);

        const int col = t * 16 + lr;
        float bv = 0.f;
        if (BIAS) bv = bias[col];
#pragma unroll
        for (int j = 0; j < 4; ++j) {
            const int orow = rbase + ko * 4 + j;
            if (orow < M) {
                float v = acc[j] + bv;
                if (ACT) v = (v >= 0.f) ? v : 0.01f * v;
                C[(long)orow * Co + col] = v;
            }
        }
    }
}

// ---------------------------------------------------------------------------
// Fused GRUCell: out = (1-z)*n + z*hp, gates [r,z,n] (PyTorch order).
// Block = 16 rows, 4 waves; wave w computes gate cols [w*96, +96) of both
// gi = x@wih^T and gh = hp@whh^T via MFMA into LDS; combine fused.
// Safe for out == x (block reads only its own rows, before the barrier).
// ---------------------------------------------------------------------------
__global__ __launch_bounds__(256) void gru_kernel(
    const float* x, const float* __restrict__ hp,
    const bf16* __restrict__ wih, const bf16* __restrict__ whh,
    const float* __restrict__ bih, const float* __restrict__ bhh,
    float* out, int N)
{
    __shared__ float Lgi[16][384];
    __shared__ float Lgh[16][384];

    const int tid  = threadIdx.x;
    const int lane = tid & 63, w = tid >> 6;
    const int lr   = lane & 15, ko = lane >> 4;
    const long r0  = (long)blockIdx.x * 16;

    long arow = r0 + lr; if (arow > N - 1) arow = N - 1;
    bf16x8 ax[4], ah[4];
#pragma unroll
    for (int kc = 0; kc < 4; ++kc) {
        ax[kc] = load8_cvt(x  + arow * 128 + kc * 32 + ko * 8);
        ah[kc] = load8_cvt(hp + arow * 128 + kc * 32 + ko * 8);
    }

#pragma unroll
    for (int t = 0; t < 6; ++t) {
        const int c0 = w * 96 + t * 16;
        f32x4 ai = {0.f, 0.f, 0.f, 0.f};
        f32x4 az = {0.f, 0.f, 0.f, 0.f};
        const bf16* wip = wih + (long)(c0 + lr) * 128 + ko * 8;
        const bf16* whp = whh + (long)(c0 + lr) * 128 + ko * 8;
#pragma unroll
        for (int kc = 0; kc < 4; ++kc) {
            ai = mfma16(ax[kc], *(const bf16x8*)(wip + kc * 32), ai);
            az = mfma16(ah[kc], *(const bf16x8*)(whp + kc * 32), az);
        }
#pragma unroll
        for (int j = 0; j < 4; ++j) {
            Lgi[ko * 4 + j][c0 + lr] = ai[j];
            Lgh[ko * 4 + j][c0 + lr] = az[j];
        }
    }
    __syncthreads();

#pragma unroll
    for (int i = 0; i < 8; ++i) {
        const int idx  = tid + 256 * i;      // 2048 = 16 rows x 128 cols
        const int lrow = idx >> 7, oc = idx & 127;
        const long row = r0 + lrow;
        if (row >= N) continue;
        const float gr  = Lgi[lrow][oc]       + Lgh[lrow][oc]       + bih[oc]       + bhh[oc];
        const float gz  = Lgi[lrow][128 + oc] + Lgh[lrow][128 + oc] + bih[128 + oc] + bhh[128 + oc];
        const float gin = Lgi[lrow][256 + oc] + bih[256 + oc];
        const float ghn = Lgh[lrow][256 + oc] + bhh[256 + oc];
        const float r = 1.f / (1.f + __expf(-gr));
        const float z = 1.f / (1.f + __expf(-gz));
        const float n = tanhf(gin + r * ghn);
        out[row * 128 + oc] = (1.f - z) * n + z * hp[row * 128 + oc];
    }
}

// ---------------------------------------------------------------------------
// GCN aggregation
// ---------------------------------------------------------------------------
__global__ void deg_kernel(const int* __restrict__ dst, float* deg, int E) {
    const int e = blockIdx.x * 256 + threadIdx.x;
    if (e < E) atomicAdd(&deg[dst[e]], 1.0f);
}

__global__ void dinv_kernel(float* dinv, int N) {
    const int i = blockIdx.x * 256 + threadIdx.x;
    if (i < N) dinv[i] = rsqrtf(dinv[i] + 1.0f);   // +1 self loop; deg+1 >= 1
}

// columns [colbase, colbase + (8<<lg)); (1<<lg) threads per edge
__global__ void scatter_kernel(const float* __restrict__ xw,
                               const int* __restrict__ src, const int* __restrict__ dst,
                               const float* __restrict__ dinv, float* __restrict__ agg,
                               int E, int colbase, int lg) {
    const long tid = (long)blockIdx.x * 256 + threadIdx.x;
    const long e = tid >> lg;
    const int  c = (int)(tid & ((1 << lg) - 1));
    if (e >= E) return;
    const long s = src[e], d = dst[e];
    const float nm = dinv[s] * dinv[d];
    const float* vp = xw + s * 128 + colbase + c * 8;
    f32x4 lo = *(const f32x4*)vp, hi = *(const f32x4*)(vp + 4);
    float* base = agg + ((d << lg) + c) * 8;     // agg row stride = 8<<lg
#pragma unroll
    for (int i = 0; i < 4; ++i) atomicAdd(base + i, lo[i] * nm);
#pragma unroll
    for (int i = 0; i < 4; ++i) atomicAdd(base + 4 + i, hi[i] * nm);
}

// out[:, cols] = leaky(agg + xw*dinv^2 + bias); out may alias agg or xw
__global__ void gcn_fin_kernel(const float* agg, const float* xw,
                               const float* __restrict__ dinv, const float* __restrict__ bias,
                               float* out, int N, int colbase, int lg) {
    const long tid = (long)blockIdx.x * 256 + threadIdx.x;
    const long i = tid >> lg;
    const int  c = (int)(tid & ((1 << lg) - 1));
    if (i >= N) return;
    const float di = dinv[i];
    const float sl = di * di;
    const int col = colbase + c * 8;
    const float* vp = xw + i * 128 + col;
    f32x4 lo = *(const f32x4*)vp, hi = *(const f32x4*)(vp + 4);
    const float* ap = agg + ((i << lg) + c) * 8;
    f32x4 o0, o1;
#pragma unroll
    for (int j = 0; j < 4; ++j) {
        float v0 = ap[j]     + lo[j] * sl + bias[col + j];
        float v1 = ap[4 + j] + hi[j] * sl + bias[col + 4 + j];
        o0[j] = (v0 >= 0.f) ? v0 : 0.01f * v0;
        o1[j] = (v1 >= 0.f) ? v1 : 0.01f * v1;
    }
    *(f32x4*)(out + i * 128 + col)     = o0;
    *(f32x4*)(out + i * 128 + col + 4) = o1;
}

// ---------------------------------------------------------------------------
// LP head: logits[e] = sum_k hs[k]*hd[k]*(w0[k]+w1[k]) + (b0+b1)
// ---------------------------------------------------------------------------
__global__ __launch_bounds__(256) void lp_kernel(
    const float* __restrict__ emb, const int* __restrict__ eli,
    const float* __restrict__ wpost, const float* __restrict__ bpost,
    float* __restrict__ logits, int EL)
{
    const int e = blockIdx.x * 256 + threadIdx.x;
    if (e >= EL) return;
    const long s = eli[e], d = eli[EL + e];
    float acc = 0.f;
#pragma unroll
    for (int c = 0; c < 32; ++c) {
        f32x4 vs = *(const f32x4*)(emb + s * 128 + c * 4);
        f32x4 vd = *(const f32x4*)(emb + d * 128 + c * 4);
        f32x4 w0 = *(const f32x4*)(wpost + c * 4);
        f32x4 w1 = *(const f32x4*)(wpost + 128 + c * 4);
#pragma unroll
        for (int i = 0; i < 4; ++i)
            acc += vs[i] * vd[i] * (w0[i] + w1[i]);
    }
    logits[e] = acc + bpost[0] + bpost[1];
}

// ---------------------------------------------------------------------------
extern "C" void kernel_launch(void* const* d_in, const int* in_sizes, int n_in,
                              void* d_out, int out_size, void* d_ws, size_t ws_size,
                              hipStream_t stream) {
    const float* x      = (const float*)d_in[0];
    const int*   ei     = (const int*)d_in[1];   // [2,E]: row0=src, row1=dst
    const int*   eli    = (const int*)d_in[2];   // [2,EL]
    const float* prev0  = (const float*)d_in[3];
    const float* prev1  = (const float*)d_in[4];
    const float* w_pre1 = (const float*)d_in[5];
    const float* b_pre1 = (const float*)d_in[6];
    const float* w_pre2 = (const float*)d_in[7];
    const float* b_pre2 = (const float*)d_in[8];
    const float* w_c1   = (const float*)d_in[9];
    const float* b_c1   = (const float*)d_in[10];
    const float* w_c2   = (const float*)d_in[11];
    const float* b_c2   = (const float*)d_in[12];
    const float* w_post = (const float*)d_in[13];
    const float* b_post = (const float*)d_in[14];
    const float* g1_wih = (const float*)d_in[15];
    const float* g1_whh = (const float*)d_in[16];
    const float* g1_bih = (const float*)d_in[17];
    const float* g1_bhh = (const float*)d_in[18];
    const float* g2_wih = (const float*)d_in[19];
    const float* g2_whh = (const float*)d_in[20];
    const float* g2_bih = (const float*)d_in[21];
    const float* g2_bhh = (const float*)d_in[22];

    const int N  = in_sizes[0] / 128;
    const int E  = in_sizes[1] / 2;
    const int EL = in_sizes[2] / 2;
    const long NH = (long)N * 128;

    // outputs (f32)
    float* out    = (float*)d_out;
    float* logits = out;
    float* emb0   = out + EL;
    float* emb1   = emb0 + NH;
    float* emb2   = emb1 + NH;

    // workspace: dinv f32[N] | bf16 weight copies | agg f32[N*cw] (conv2)
    char*  ws   = (char*)d_ws;
    float* dinv = (float*)ws;
    size_t off  = (((size_t)N * 4) + 255) & ~(size_t)255;
    bf16* wb_pre1 = (bf16*)(ws + off);            // 32768
    bf16* wb_pre2 = wb_pre1 + 32768;              // 32768
    bf16* wb_c1   = wb_pre2 + 32768;              // 16384
    bf16* wb_c2   = wb_c1 + 16384;                // 16384
    bf16* wb_g1i  = wb_c2 + 16384;                // 49152
    bf16* wb_g1h  = wb_g1i + 49152;               // 49152
    bf16* wb_g2i  = wb_g1h + 49152;               // 49152
    bf16* wb_g2h  = wb_g2i + 49152;               // 49152
    size_t off2 = off + ((294912 * 2 + 255) & ~(size_t)255);
    float* wsagg = (float*)(ws + off2);
    const size_t wsavail = (ws_size > off2) ? ws_size - off2 : 0;

    const int gB = 256;
    const dim3 blk(gB);
    const int grid_rows64 = (N + 63) / 64;
    const int grid_gru    = (N + 15) / 16;

    // weight bf16 pre-conversion
    cvt_kernel<<<(32768 + 255) / 256, blk, 0, stream>>>(w_pre1, wb_pre1, 32768);
    cvt_kernel<<<(32768 + 255) / 256, blk, 0, stream>>>(w_pre2, wb_pre2, 32768);
    cvt_kernel<<<(16384 + 255) / 256, blk, 0, stream>>>(w_c1, wb_c1, 16384);
    cvt_kernel<<<(16384 + 255) / 256, blk, 0, stream>>>(w_c2, wb_c2, 16384);
    cvt_kernel<<<(49152 + 255) / 256, blk, 0, stream>>>(g1_wih, wb_g1i, 49152);
    cvt_kernel<<<(49152 + 255) / 256, blk, 0, stream>>>(g1_whh, wb_g1h, 49152);
    cvt_kernel<<<(49152 + 255) / 256, blk, 0, stream>>>(g2_wih, wb_g2i, 49152);
    cvt_kernel<<<(49152 + 255) / 256, blk, 0, stream>>>(g2_whh, wb_g2h, 49152);

    // degree -> dinv (shared by both convs)
    hipMemsetAsync(dinv, 0, (size_t)N * 4, stream);
    deg_kernel<<<(E + gB - 1) / gB, blk, 0, stream>>>(ei + E, dinv, E);
    dinv_kernel<<<(N + gB - 1) / gB, blk, 0, stream>>>(dinv, N);

    // preprocess: H1 [N,256] across emb1+emb2 slots; H2 [N,128] -> emb0
    gemm_kernel<128, 256, true, true><<<grid_rows64, blk, 0, stream>>>(x, wb_pre1, b_pre1, emb1, N);
    gemm_kernel<256, 128, true, true><<<grid_rows64, blk, 0, stream>>>(emb1, wb_pre2, b_pre2, emb0, N);

    // GRU1: emb0 = gru(H2, prev0)  (in place)
    gru_kernel<<<grid_gru, blk, 0, stream>>>(emb0, prev0, wb_g1i, wb_g1h, g1_bih, g1_bhh, emb0, N);

    // conv: xw staged in xwbuf; agg in aggbuf (may alias aout)
    auto run_conv = [&](const float* hin, const bf16* wcb, const float* bc,
                        float* xwbuf, float* aggbuf, float* aout, int cw) {
        gemm_kernel<128, 128, false, false><<<grid_rows64, blk, 0, stream>>>(hin, wcb, nullptr, xwbuf, N);
        const int lg = __builtin_ctz(cw >> 3);
        const int passes = 128 / cw;
        const int grid_sc = (int)((((long)E << lg) + gB - 1) / gB);
        const int grid_fn = (int)((((long)N << lg) + gB - 1) / gB);
        for (int p = 0; p < passes; ++p) {
            const int colbase = p * cw;
            hipMemsetAsync(aggbuf, 0, (size_t)N * cw * 4, stream);
            scatter_kernel<<<grid_sc, blk, 0, stream>>>(xwbuf, ei, ei + E, dinv, aggbuf, E, colbase, lg);
            gcn_fin_kernel<<<grid_fn, blk, 0, stream>>>(aggbuf, xwbuf, dinv, bc, aout, N, colbase, lg);
        }
    };

    // conv1: xw -> emb2 slot, agg -> dead emb1 slot (finalize in place), out emb1
    run_conv(emb0, wb_c1, b_c1, emb2, emb1, emb1, 128);
    gru_kernel<<<grid_gru, blk, 0, stream>>>(emb1, prev0, wb_g1i, wb_g1h, g1_bih, g1_bhh, emb1, N);

    // conv2: xw -> emb2 slot, agg -> ws (column passes if ws small), out emb2
    int cw2 = 128;
    while (cw2 > 8 && (size_t)N * cw2 * 4 > wsavail) cw2 >>= 1;
    run_conv(emb1, wb_c2, b_c2, emb2, wsagg, emb2, cw2);
    gru_kernel<<<grid_gru, blk, 0, stream>>>(emb2, prev1, wb_g2i, wb_g2h, g2_bih, g2_bhh, emb2, N);

    // LP head
    lp_kernel<<<(EL + gB - 1) / gB, blk, 0, stream>>>(emb2, eli, w_post, b_post, logits, EL);
}

// Round 4
// 1049.082 us; speedup vs baseline: 5.0234x; 5.0234x over previous
//
#include <hip/hip_runtime.h>
#include <hip/hip_bf16.h>

// ---------------------------------------------------------------------------
// ROLAND GNN forward. Device buffers FLOAT32; matmuls bf16-MFMA, f32 accum.
// Outputs (concat, f32): logits[EL], emb0[N,128], emb1[N,128], emb2[N,128]
// Round 4: CSR-gather aggregation (no atomics on the feature matrix).
//   ws: dinv | degi | inc | rowptr | cursor | bsum | bf16 weights |
//       csr_src[E] | csr_norm[E] | xwb bf16[N*cw]
// ---------------------------------------------------------------------------

typedef __bf16 bf16;
typedef __bf16 bf16x8 __attribute__((ext_vector_type(8)));
typedef float  f32x4  __attribute__((ext_vector_type(4)));

#define DEV __device__ __forceinline__

DEV f32x4 mfma16(bf16x8 a, bf16x8 b, f32x4 c) {
    return __builtin_amdgcn_mfma_f32_16x16x32_bf16(a, b, c, 0, 0, 0);
}

DEV bf16x8 load8_cvt(const float* p) {
    f32x4 lo = *(const f32x4*)p;
    f32x4 hi = *(const f32x4*)(p + 4);
    bf16x8 v;
    v[0] = (bf16)lo[0]; v[1] = (bf16)lo[1]; v[2] = (bf16)lo[2]; v[3] = (bf16)lo[3];
    v[4] = (bf16)hi[0]; v[5] = (bf16)hi[1]; v[6] = (bf16)hi[2]; v[7] = (bf16)hi[3];
    return v;
}

__global__ void cvt_kernel(const float* __restrict__ in, bf16* __restrict__ ob, int n) {
    const int i = blockIdx.x * 256 + threadIdx.x;
    if (i < n) ob[i] = (bf16)in[i];
}

// ---------------------------------------------------------------------------
// GEMM: C[M,Co] = act(A[M,Ci] @ W[Co,Ci]^T + bias). A f32, W bf16, out OT.
// block = 256 (4 waves); wave w owns rows [blk*64 + w*16, +16).
// MFMA 16x16x32 bf16; C/D layout (m89): col=lane&15, row=4*(lane>>4)+j.
// ---------------------------------------------------------------------------
template<int Ci, int Co, bool ACT, bool BIAS, typename OT>
__global__ __launch_bounds__(256) void gemm_kernel(
    const float* __restrict__ A, const bf16* __restrict__ W,
    const float* __restrict__ bias, OT* __restrict__ C, int M)
{
    const int tid  = threadIdx.x;
    const int lane = tid & 63, w = tid >> 6;
    const int lr   = lane & 15, ko = lane >> 4;
    const int rbase = blockIdx.x * 64 + w * 16;

    long arow = rbase + lr; if (arow > M - 1) arow = M - 1;  // clamped rows never stored
    constexpr int KC = Ci / 32;
    constexpr int NT = Co / 16;

    bf16x8 a[KC];
#pragma unroll
    for (int kc = 0; kc < KC; ++kc)
        a[kc] = load8_cvt(A + arow * Ci + kc * 32 + ko * 8);

#pragma unroll
    for (int t = 0; t < NT; ++t) {
        f32x4 acc = {0.f, 0.f, 0.f, 0.f};
        const bf16* wp = W + (long)(t * 16 + lr) * Ci + ko * 8;
#pragma unroll
        for (int kc = 0; kc < KC; ++kc)
            acc = mfma16(a[kc], *(const bf16x8*)(wp + kc * 32), acc);

        const int col = t * 16 + lr;
        float bv = 0.f;
        if (BIAS) bv = bias[col];
#pragma unroll
        for (int j = 0; j < 4; ++j) {
            const int orow = rbase + ko * 4 + j;
            if (orow < M) {
                float v = acc[j] + bv;
                if (ACT) v = (v >= 0.f) ? v : 0.01f * v;
                C[(long)orow * Co + col] = (OT)v;
            }
        }
    }
}

// ---------------------------------------------------------------------------
// Fused GRUCell (unchanged from round 3): out = (1-z)*n + z*hp.
// ---------------------------------------------------------------------------
__global__ __launch_bounds__(256) void gru_kernel(
    const float* x, const float* __restrict__ hp,
    const bf16* __restrict__ wih, const bf16* __restrict__ whh,
    const float* __restrict__ bih, const float* __restrict__ bhh,
    float* out, int N)
{
    __shared__ float Lgi[16][384];
    __shared__ float Lgh[16][384];

    const int tid  = threadIdx.x;
    const int lane = tid & 63, w = tid >> 6;
    const int lr   = lane & 15, ko = lane >> 4;
    const long r0  = (long)blockIdx.x * 16;

    long arow = r0 + lr; if (arow > N - 1) arow = N - 1;
    bf16x8 ax[4], ah[4];
#pragma unroll
    for (int kc = 0; kc < 4; ++kc) {
        ax[kc] = load8_cvt(x  + arow * 128 + kc * 32 + ko * 8);
        ah[kc] = load8_cvt(hp + arow * 128 + kc * 32 + ko * 8);
    }

#pragma unroll
    for (int t = 0; t < 6; ++t) {
        const int c0 = w * 96 + t * 16;
        f32x4 ai = {0.f, 0.f, 0.f, 0.f};
        f32x4 az = {0.f, 0.f, 0.f, 0.f};
        const bf16* wip = wih + (long)(c0 + lr) * 128 + ko * 8;
        const bf16* whp = whh + (long)(c0 + lr) * 128 + ko * 8;
#pragma unroll
        for (int kc = 0; kc < 4; ++kc) {
            ai = mfma16(ax[kc], *(const bf16x8*)(wip + kc * 32), ai);
            az = mfma16(ah[kc], *(const bf16x8*)(whp + kc * 32), az);
        }
#pragma unroll
        for (int j = 0; j < 4; ++j) {
            Lgi[ko * 4 + j][c0 + lr] = ai[j];
            Lgh[ko * 4 + j][c0 + lr] = az[j];
        }
    }
    __syncthreads();

#pragma unroll
    for (int i = 0; i < 8; ++i) {
        const int idx  = tid + 256 * i;
        const int lrow = idx >> 7, oc = idx & 127;
        const long row = r0 + lrow;
        if (row >= N) continue;
        const float gr  = Lgi[lrow][oc]       + Lgh[lrow][oc]       + bih[oc]       + bhh[oc];
        const float gz  = Lgi[lrow][128 + oc] + Lgh[lrow][128 + oc] + bih[128 + oc] + bhh[128 + oc];
        const float gin = Lgi[lrow][256 + oc] + bih[256 + oc];
        const float ghn = Lgh[lrow][256 + oc] + bhh[256 + oc];
        const float r = 1.f / (1.f + __expf(-gr));
        const float z = 1.f / (1.f + __expf(-gz));
        const float n = tanhf(gin + r * ghn);
        out[row * 128 + oc] = (1.f - z) * n + z * hp[row * 128 + oc];
    }
}

// ---------------------------------------------------------------------------
// CSR build
// ---------------------------------------------------------------------------
__global__ void deg_kernel(const int* __restrict__ dst, int* degi, int E) {
    const int e = blockIdx.x * 256 + threadIdx.x;
    if (e < E) atomicAdd(&degi[dst[e]], 1);
}

__global__ void dinv_kernel(const int* __restrict__ degi, float* __restrict__ dinv, int N) {
    const int i = blockIdx.x * 256 + threadIdx.x;
    if (i < N) dinv[i] = rsqrtf((float)degi[i] + 1.0f);   // +1 self loop
}

// block-level inclusive scan (Hillis-Steele, 256)
__global__ void scan1_kernel(const int* __restrict__ degi, int* __restrict__ inc,
                             int* __restrict__ bsum, int N) {
    __shared__ int s[256];
    const int i = blockIdx.x * 256 + threadIdx.x;
    s[threadIdx.x] = (i < N) ? degi[i] : 0;
    __syncthreads();
#pragma unroll
    for (int off = 1; off < 256; off <<= 1) {
        int t = (threadIdx.x >= off) ? s[threadIdx.x - off] : 0;
        __syncthreads();
        s[threadIdx.x] += t;
        __syncthreads();
    }
    if (i < N) inc[i] = s[threadIdx.x];
    if (threadIdx.x == 255) bsum[blockIdx.x] = s[255];
}

// single-block inclusive scan of block sums (chunked, with carry)
__global__ void scan2_kernel(int* bsum, int nb) {
    __shared__ int s[512];
    __shared__ int carry;
    if (threadIdx.x == 0) carry = 0;
    __syncthreads();
    for (int base = 0; base < nb; base += 512) {
        const int i = base + threadIdx.x;
        s[threadIdx.x] = (i < nb) ? bsum[i] : 0;
        __syncthreads();
#pragma unroll
        for (int off = 1; off < 512; off <<= 1) {
            int t = (threadIdx.x >= off) ? s[threadIdx.x - off] : 0;
            __syncthreads();
            s[threadIdx.x] += t;
            __syncthreads();
        }
        const int c = carry;
        if (i < nb) bsum[i] = s[threadIdx.x] + c;
        __syncthreads();
        if (threadIdx.x == 511) carry = c + s[511];
        __syncthreads();
    }
}

__global__ void scan3_kernel(const int* __restrict__ inc, const int* __restrict__ degi,
                             const int* __restrict__ bsum, int* __restrict__ rowptr, int N) {
    const int i = blockIdx.x * 256 + threadIdx.x;
    if (i >= N) return;
    const int prev = (blockIdx.x > 0) ? bsum[blockIdx.x - 1] : 0;
    rowptr[i] = prev + inc[i] - degi[i];   // exclusive prefix
}

__global__ void fill_kernel(const int* __restrict__ src, const int* __restrict__ dst,
                            const int* __restrict__ rowptr, int* cursor,
                            const float* __restrict__ dinv,
                            int* __restrict__ csr_src, float* __restrict__ csr_norm, int E) {
    const int e = blockIdx.x * 256 + threadIdx.x;
    if (e >= E) return;
    const int s = src[e], d = dst[e];
    const int pos = rowptr[d] + atomicAdd(&cursor[d], 1);
    csr_src[pos]  = s;
    csr_norm[pos] = dinv[s] * dinv[d];
}

// ---------------------------------------------------------------------------
// Fused gather + finalize: out[d, cols] = leaky(sum_in xwb[s]*nm + xwb[d]*di^2 + b)
// (1<<lg) lanes per node, each owns 8 columns of this pass.
// ---------------------------------------------------------------------------
__global__ __launch_bounds__(256) void gather_kernel(
    const bf16* __restrict__ xwb,            // [N, cw] bf16
    const int* __restrict__ rowptr, const int* __restrict__ degi,
    const int* __restrict__ csr_src, const float* __restrict__ csr_norm,
    const float* __restrict__ dinv, const float* __restrict__ bias,
    float* __restrict__ out, int N, int colbase, int cw, int lg)
{
    const long tid = (long)blockIdx.x * 256 + threadIdx.x;
    const long d = tid >> lg;
    const int  c = (int)(tid & ((1 << lg) - 1));
    if (d >= N) return;

    float acc[8] = {0.f, 0.f, 0.f, 0.f, 0.f, 0.f, 0.f, 0.f};
    const int start = rowptr[d];
    const int deg   = degi[d];
    for (int k = 0; k < deg; ++k) {
        const int   s  = csr_src[start + k];
        const float nm = csr_norm[start + k];
        bf16x8 v = *(const bf16x8*)(xwb + (long)s * cw + c * 8);
#pragma unroll
        for (int j = 0; j < 8; ++j) acc[j] += (float)v[j] * nm;
    }

    const float di = dinv[d], sl = di * di;
    bf16x8 vd = *(const bf16x8*)(xwb + d * cw + c * 8);
    const int col = colbase + c * 8;
    f32x4 o0, o1;
#pragma unroll
    for (int j = 0; j < 4; ++j) {
        float v0 = acc[j]     + (float)vd[j]     * sl + bias[col + j];
        float v1 = acc[4 + j] + (float)vd[4 + j] * sl + bias[col + 4 + j];
        o0[j] = (v0 >= 0.f) ? v0 : 0.01f * v0;
        o1[j] = (v1 >= 0.f) ? v1 : 0.01f * v1;
    }
    *(f32x4*)(out + d * 128 + col)     = o0;
    *(f32x4*)(out + d * 128 + col + 4) = o1;
}

// ---------------------------------------------------------------------------
// LP head
// ---------------------------------------------------------------------------
__global__ __launch_bounds__(256) void lp_kernel(
    const float* __restrict__ emb, const int* __restrict__ eli,
    const float* __restrict__ wpost, const float* __restrict__ bpost,
    float* __restrict__ logits, int EL)
{
    const int e = blockIdx.x * 256 + threadIdx.x;
    if (e >= EL) return;
    const long s = eli[e], d = eli[EL + e];
    float acc = 0.f;
#pragma unroll
    for (int c = 0; c < 32; ++c) {
        f32x4 vs = *(const f32x4*)(emb + s * 128 + c * 4);
        f32x4 vd = *(const f32x4*)(emb + d * 128 + c * 4);
        f32x4 w0 = *(const f32x4*)(wpost + c * 4);
        f32x4 w1 = *(const f32x4*)(wpost + 128 + c * 4);
#pragma unroll
        for (int i = 0; i < 4; ++i)
            acc += vs[i] * vd[i] * (w0[i] + w1[i]);
    }
    logits[e] = acc + bpost[0] + bpost[1];
}

// ---------------------------------------------------------------------------
extern "C" void kernel_launch(void* const* d_in, const int* in_sizes, int n_in,
                              void* d_out, int out_size, void* d_ws, size_t ws_size,
                              hipStream_t stream) {
    const float* x      = (const float*)d_in[0];
    const int*   ei     = (const int*)d_in[1];   // [2,E]: row0=src, row1=dst
    const int*   eli    = (const int*)d_in[2];
    const float* prev0  = (const float*)d_in[3];
    const float* prev1  = (const float*)d_in[4];
    const float* w_pre1 = (const float*)d_in[5];
    const float* b_pre1 = (const float*)d_in[6];
    const float* w_pre2 = (const float*)d_in[7];
    const float* b_pre2 = (const float*)d_in[8];
    const float* w_c1   = (const float*)d_in[9];
    const float* b_c1   = (const float*)d_in[10];
    const float* w_c2   = (const float*)d_in[11];
    const float* b_c2   = (const float*)d_in[12];
    const float* w_post = (const float*)d_in[13];
    const float* b_post = (const float*)d_in[14];
    const float* g1_wih = (const float*)d_in[15];
    const float* g1_whh = (const float*)d_in[16];
    const float* g1_bih = (const float*)d_in[17];
    const float* g1_bhh = (const float*)d_in[18];
    const float* g2_wih = (const float*)d_in[19];
    const float* g2_whh = (const float*)d_in[20];
    const float* g2_bih = (const float*)d_in[21];
    const float* g2_bhh = (const float*)d_in[22];

    const int N  = in_sizes[0] / 128;
    const int E  = in_sizes[1] / 2;
    const int EL = in_sizes[2] / 2;
    const long NH = (long)N * 128;

    // outputs (f32)
    float* out    = (float*)d_out;
    float* logits = out;
    float* emb0   = out + EL;
    float* emb1   = emb0 + NH;
    float* emb2   = emb1 + NH;

    // ---- workspace layout ----
    char* ws = (char*)d_ws;
    size_t p = 0;
    auto alloc = [&](size_t bytes) { size_t o = p; p = (p + bytes + 255) & ~(size_t)255; return o; };
    float* dinv    = (float*)(ws + alloc((size_t)N * 4));
    int*   degi    = (int*)  (ws + alloc((size_t)N * 4));
    int*   inc     = (int*)  (ws + alloc((size_t)N * 4));
    int*   rowptr  = (int*)  (ws + alloc((size_t)N * 4));
    int*   cursor  = (int*)  (ws + alloc((size_t)N * 4));
    int*   bsum    = (int*)  (ws + alloc(4096));
    bf16*  wb      = (bf16*) (ws + alloc((size_t)294912 * 2));
    int*   csr_src = (int*)  (ws + alloc((size_t)E * 4));
    float* csr_nrm = (float*)(ws + alloc((size_t)E * 4));
    const size_t fixed = p;
    bf16*  xwb     = (bf16*)(ws + fixed);

    // xw columns per pass, limited by remaining ws
    int cw = 128;
    while (cw > 16 && fixed + (size_t)N * cw * 2 > ws_size) cw >>= 1;
    const int lg = __builtin_ctz(cw >> 3);
    const int passes = 128 / cw;

    // bf16 weight copies (packed into wb)
    bf16* wb_pre1 = wb;                  // 32768
    bf16* wb_pre2 = wb_pre1 + 32768;     // 32768
    bf16* wb_c1   = wb_pre2 + 32768;     // 16384
    bf16* wb_c2   = wb_c1 + 16384;       // 16384
    bf16* wb_g1i  = wb_c2 + 16384;       // 49152
    bf16* wb_g1h  = wb_g1i + 49152;      // 49152
    bf16* wb_g2i  = wb_g1h + 49152;      // 49152
    bf16* wb_g2h  = wb_g2i + 49152;      // 49152

    const int gB = 256;
    const dim3 blk(gB);
    const int grid_rows64 = (N + 63) / 64;
    const int grid_gru    = (N + 15) / 16;
    const int grid_E      = (E + gB - 1) / gB;
    const int grid_N      = (N + gB - 1) / gB;
    const int nb          = (N + 255) / 256;

    cvt_kernel<<<(32768 + 255) / 256, blk, 0, stream>>>(w_pre1, wb_pre1, 32768);
    cvt_kernel<<<(32768 + 255) / 256, blk, 0, stream>>>(w_pre2, wb_pre2, 32768);
    cvt_kernel<<<(16384 + 255) / 256, blk, 0, stream>>>(w_c1, wb_c1, 16384);
    cvt_kernel<<<(16384 + 255) / 256, blk, 0, stream>>>(w_c2, wb_c2, 16384);
    cvt_kernel<<<(49152 + 255) / 256, blk, 0, stream>>>(g1_wih, wb_g1i, 49152);
    cvt_kernel<<<(49152 + 255) / 256, blk, 0, stream>>>(g1_whh, wb_g1h, 49152);
    cvt_kernel<<<(49152 + 255) / 256, blk, 0, stream>>>(g2_wih, wb_g2i, 49152);
    cvt_kernel<<<(49152 + 255) / 256, blk, 0, stream>>>(g2_whh, wb_g2h, 49152);

    // ---- CSR build (once; reused by both convs) ----
    hipMemsetAsync(degi, 0, (size_t)N * 4, stream);
    deg_kernel<<<grid_E, blk, 0, stream>>>(ei + E, degi, E);
    dinv_kernel<<<grid_N, blk, 0, stream>>>(degi, dinv, N);
    scan1_kernel<<<nb, blk, 0, stream>>>(degi, inc, bsum, N);
    scan2_kernel<<<1, 512, 0, stream>>>(bsum, nb);
    scan3_kernel<<<nb, blk, 0, stream>>>(inc, degi, bsum, rowptr, N);
    hipMemsetAsync(cursor, 0, (size_t)N * 4, stream);
    fill_kernel<<<grid_E, blk, 0, stream>>>(ei, ei + E, rowptr, cursor, dinv, csr_src, csr_nrm, E);

    // ---- preprocess: H1 [N,256] across emb1+emb2 slots; H2 -> emb0 ----
    gemm_kernel<128, 256, true, true, float><<<grid_rows64, blk, 0, stream>>>(x, wb_pre1, b_pre1, emb1, N);
    gemm_kernel<256, 128, true, true, float><<<grid_rows64, blk, 0, stream>>>(emb1, wb_pre2, b_pre2, emb0, N);

    // GRU1: emb0 = gru(H2, prev0) (in place)
    gru_kernel<<<grid_gru, blk, 0, stream>>>(emb0, prev0, wb_g1i, wb_g1h, g1_bih, g1_bhh, emb0, N);

    // ---- conv via CSR gather ----
    const int grid_ga = (int)((((long)N << lg) + gB - 1) / gB);
    auto run_conv = [&](const float* hin, const bf16* wfull, const float* bc, float* aout) {
        for (int ps = 0; ps < passes; ++ps) {
            const int colbase = ps * cw;
            const bf16* wp = wfull + (size_t)colbase * 128;
            switch (cw) {
            case 128: gemm_kernel<128, 128, false, false, bf16><<<grid_rows64, blk, 0, stream>>>(hin, wp, nullptr, xwb, N); break;
            case 64:  gemm_kernel<128, 64,  false, false, bf16><<<grid_rows64, blk, 0, stream>>>(hin, wp, nullptr, xwb, N); break;
            case 32:  gemm_kernel<128, 32,  false, false, bf16><<<grid_rows64, blk, 0, stream>>>(hin, wp, nullptr, xwb, N); break;
            default:  gemm_kernel<128, 16,  false, false, bf16><<<grid_rows64, blk, 0, stream>>>(hin, wp, nullptr, xwb, N); break;
            }
            gather_kernel<<<grid_ga, blk, 0, stream>>>(xwb, rowptr, degi, csr_src, csr_nrm,
                                                       dinv, bc, aout, N, colbase, cw, lg);
        }
    };

    // conv1 -> emb1; GRU2 in place
    run_conv(emb0, wb_c1, b_c1, emb1);
    gru_kernel<<<grid_gru, blk, 0, stream>>>(emb1, prev0, wb_g1i, wb_g1h, g1_bih, g1_bhh, emb1, N);

    // conv2 -> emb2; GRU3 in place
    run_conv(emb1, wb_c2, b_c2, emb2);
    gru_kernel<<<grid_gru, blk, 0, stream>>>(emb2, prev1, wb_g2i, wb_g2h, g2_bih, g2_bhh, emb2, N);

    // LP head
    lp_kernel<<<(EL + gB - 1) / gB, blk, 0, stream>>>(emb2, eli, w_post, b_post, logits, EL);
}

// Round 5
// 963.004 us; speedup vs baseline: 5.4724x; 1.0894x over previous
//
#include <hip/hip_runtime.h>
#include <hip/hip_bf16.h>

// ---------------------------------------------------------------------------
// ROLAND GNN forward. Device buffers FLOAT32; matmuls bf16-MFMA, f32 accum.
// Outputs (concat, f32): logits[EL], emb0[N,128], emb1[N,128], emb2[N,128]
// Round 5: all-register GRU (no LDS, no barriers, register-local gate combine).
// ---------------------------------------------------------------------------

typedef __bf16 bf16;
typedef __bf16 bf16x8 __attribute__((ext_vector_type(8)));
typedef float  f32x4  __attribute__((ext_vector_type(4)));

#define DEV __device__ __forceinline__

DEV f32x4 mfma16(bf16x8 a, bf16x8 b, f32x4 c) {
    return __builtin_amdgcn_mfma_f32_16x16x32_bf16(a, b, c, 0, 0, 0);
}

DEV bf16x8 load8_cvt(const float* p) {
    f32x4 lo = *(const f32x4*)p;
    f32x4 hi = *(const f32x4*)(p + 4);
    bf16x8 v;
    v[0] = (bf16)lo[0]; v[1] = (bf16)lo[1]; v[2] = (bf16)lo[2]; v[3] = (bf16)lo[3];
    v[4] = (bf16)hi[0]; v[5] = (bf16)hi[1]; v[6] = (bf16)hi[2]; v[7] = (bf16)hi[3];
    return v;
}

__global__ void cvt_kernel(const float* __restrict__ in, bf16* __restrict__ ob, int n) {
    const int i = blockIdx.x * 256 + threadIdx.x;
    if (i < n) ob[i] = (bf16)in[i];
}

// ---------------------------------------------------------------------------
// GEMM: C[M,Co] = act(A[M,Ci] @ W[Co,Ci]^T + bias). A f32, W bf16, out OT.
// ---------------------------------------------------------------------------
template<int Ci, int Co, bool ACT, bool BIAS, typename OT>
__global__ __launch_bounds__(256) void gemm_kernel(
    const float* __restrict__ A, const bf16* __restrict__ W,
    const float* __restrict__ bias, OT* __restrict__ C, int M)
{
    const int tid  = threadIdx.x;
    const int lane = tid & 63, w = tid >> 6;
    const int lr   = lane & 15, ko = lane >> 4;
    const int rbase = blockIdx.x * 64 + w * 16;

    long arow = rbase + lr; if (arow > M - 1) arow = M - 1;  // clamped rows never stored
    constexpr int KC = Ci / 32;
    constexpr int NT = Co / 16;

    bf16x8 a[KC];
#pragma unroll
    for (int kc = 0; kc < KC; ++kc)
        a[kc] = load8_cvt(A + arow * Ci + kc * 32 + ko * 8);

#pragma unroll
    for (int t = 0; t < NT; ++t) {
        f32x4 acc = {0.f, 0.f, 0.f, 0.f};
        const bf16* wp = W + (long)(t * 16 + lr) * Ci + ko * 8;
#pragma unroll
        for (int kc = 0; kc < KC; ++kc)
            acc = mfma16(a[kc], *(const bf16x8*)(wp + kc * 32), acc);

        const int col = t * 16 + lr;
        float bv = 0.f;
        if (BIAS) bv = bias[col];
#pragma unroll
        for (int j = 0; j < 4; ++j) {
            const int orow = rbase + ko * 4 + j;
            if (orow < M) {
                float v = acc[j] + bv;
                if (ACT) v = (v >= 0.f) ? v : 0.01f * v;
                C[(long)orow * Co + col] = (OT)v;
            }
        }
    }
}

// ---------------------------------------------------------------------------
// All-register GRUCell: out = (1-z)*n + z*hp, gates [r,z,n] (PyTorch order).
// One wave owns 16 rows. Per column-tile tc (16 cols), compute 4 accumulators:
//   r_pre = x@wih_r^T + hp@whh_r^T   (fused into one MFMA chain)
//   z_pre likewise; gin = x@wih_n^T; ghn = hp@whh_n^T
// C/D layout (m89): col=lane&15, row=4*(lane>>4)+j -> gate combine is fully
// register-local per lane. No LDS, no barriers. Safe for out == x.
// ---------------------------------------------------------------------------
__global__ __launch_bounds__(256) void gru_kernel(
    const float* x, const float* __restrict__ hp,
    const bf16* __restrict__ wih, const bf16* __restrict__ whh,
    const float* __restrict__ bih, const float* __restrict__ bhh,
    float* out, int N)
{
    const int tid  = threadIdx.x;
    const int lane = tid & 63, w = tid >> 6;
    const int lr   = lane & 15, ko = lane >> 4;
    const long rbase = ((long)blockIdx.x * 4 + w) * 16;
    if (rbase >= N) return;

    long arow = rbase + lr; if (arow > N - 1) arow = N - 1;
    bf16x8 ax[4], ah[4];
#pragma unroll
    for (int kc = 0; kc < 4; ++kc) {
        ax[kc] = load8_cvt(x  + arow * 128 + kc * 32 + ko * 8);
        ah[kc] = load8_cvt(hp + arow * 128 + kc * 32 + ko * 8);
    }

#pragma unroll
    for (int tc = 0; tc < 8; ++tc) {
        const int col = tc * 16 + lr;
        const bf16* wr_i = wih + (long)(col)       * 128 + ko * 8;
        const bf16* wr_h = whh + (long)(col)       * 128 + ko * 8;
        const bf16* wz_i = wih + (long)(128 + col) * 128 + ko * 8;
        const bf16* wz_h = whh + (long)(128 + col) * 128 + ko * 8;
        const bf16* wn_i = wih + (long)(256 + col) * 128 + ko * 8;
        const bf16* wn_h = whh + (long)(256 + col) * 128 + ko * 8;

        f32x4 ar = {0.f, 0.f, 0.f, 0.f};
        f32x4 az = {0.f, 0.f, 0.f, 0.f};
        f32x4 ai = {0.f, 0.f, 0.f, 0.f};
        f32x4 ag = {0.f, 0.f, 0.f, 0.f};
#pragma unroll
        for (int kc = 0; kc < 4; ++kc) {
            ar = mfma16(ax[kc], *(const bf16x8*)(wr_i + kc * 32), ar);
            ar = mfma16(ah[kc], *(const bf16x8*)(wr_h + kc * 32), ar);
            az = mfma16(ax[kc], *(const bf16x8*)(wz_i + kc * 32), az);
            az = mfma16(ah[kc], *(const bf16x8*)(wz_h + kc * 32), az);
            ai = mfma16(ax[kc], *(const bf16x8*)(wn_i + kc * 32), ai);
            ag = mfma16(ah[kc], *(const bf16x8*)(wn_h + kc * 32), ag);
        }

        const float br = bih[col]       + bhh[col];
        const float bz = bih[128 + col] + bhh[128 + col];
        const float bi = bih[256 + col];
        const float bh = bhh[256 + col];
#pragma unroll
        for (int j = 0; j < 4; ++j) {
            const long row = rbase + ko * 4 + j;
            if (row < N) {
                const float r = 1.f / (1.f + __expf(-(ar[j] + br)));
                const float z = 1.f / (1.f + __expf(-(az[j] + bz)));
                const float pre = (ai[j] + bi) + r * (ag[j] + bh);
                const float n = 1.f - 2.f / (1.f + __expf(2.f * pre));
                out[row * 128 + col] = (1.f - z) * n + z * hp[row * 128 + col];
            }
        }
    }
}

// ---------------------------------------------------------------------------
// CSR build
// ---------------------------------------------------------------------------
__global__ void deg_kernel(const int* __restrict__ dst, int* degi, int E) {
    const int e = blockIdx.x * 256 + threadIdx.x;
    if (e < E) atomicAdd(&degi[dst[e]], 1);
}

__global__ void dinv_kernel(const int* __restrict__ degi, float* __restrict__ dinv, int N) {
    const int i = blockIdx.x * 256 + threadIdx.x;
    if (i < N) dinv[i] = rsqrtf((float)degi[i] + 1.0f);   // +1 self loop
}

__global__ void scan1_kernel(const int* __restrict__ degi, int* __restrict__ inc,
                             int* __restrict__ bsum, int N) {
    __shared__ int s[256];
    const int i = blockIdx.x * 256 + threadIdx.x;
    s[threadIdx.x] = (i < N) ? degi[i] : 0;
    __syncthreads();
#pragma unroll
    for (int off = 1; off < 256; off <<= 1) {
        int t = (threadIdx.x >= off) ? s[threadIdx.x - off] : 0;
        __syncthreads();
        s[threadIdx.x] += t;
        __syncthreads();
    }
    if (i < N) inc[i] = s[threadIdx.x];
    if (threadIdx.x == 255) bsum[blockIdx.x] = s[255];
}

__global__ void scan2_kernel(int* bsum, int nb) {
    __shared__ int s[512];
    __shared__ int carry;
    if (threadIdx.x == 0) carry = 0;
    __syncthreads();
    for (int base = 0; base < nb; base += 512) {
        const int i = base + threadIdx.x;
        s[threadIdx.x] = (i < nb) ? bsum[i] : 0;
        __syncthreads();
#pragma unroll
        for (int off = 1; off < 512; off <<= 1) {
            int t = (threadIdx.x >= off) ? s[threadIdx.x - off] : 0;
            __syncthreads();
            s[threadIdx.x] += t;
            __syncthreads();
        }
        const int c = carry;
        if (i < nb) bsum[i] = s[threadIdx.x] + c;
        __syncthreads();
        if (threadIdx.x == 511) carry = c + s[511];
        __syncthreads();
    }
}

__global__ void scan3_kernel(const int* __restrict__ inc, const int* __restrict__ degi,
                             const int* __restrict__ bsum, int* __restrict__ rowptr, int N) {
    const int i = blockIdx.x * 256 + threadIdx.x;
    if (i >= N) return;
    const int prev = (blockIdx.x > 0) ? bsum[blockIdx.x - 1] : 0;
    rowptr[i] = prev + inc[i] - degi[i];   // exclusive prefix
}

__global__ void fill_kernel(const int* __restrict__ src, const int* __restrict__ dst,
                            const int* __restrict__ rowptr, int* cursor,
                            const float* __restrict__ dinv,
                            int* __restrict__ csr_src, float* __restrict__ csr_norm, int E) {
    const int e = blockIdx.x * 256 + threadIdx.x;
    if (e >= E) return;
    const int s = src[e], d = dst[e];
    const int pos = rowptr[d] + atomicAdd(&cursor[d], 1);
    csr_src[pos]  = s;
    csr_norm[pos] = dinv[s] * dinv[d];
}

// ---------------------------------------------------------------------------
// Fused gather + finalize: out[d, cols] = leaky(sum_in xwb[s]*nm + xwb[d]*di^2 + b)
// ---------------------------------------------------------------------------
__global__ __launch_bounds__(256) void gather_kernel(
    const bf16* __restrict__ xwb,            // [N, cw] bf16
    const int* __restrict__ rowptr, const int* __restrict__ degi,
    const int* __restrict__ csr_src, const float* __restrict__ csr_norm,
    const float* __restrict__ dinv, const float* __restrict__ bias,
    float* __restrict__ out, int N, int colbase, int cw, int lg)
{
    const long tid = (long)blockIdx.x * 256 + threadIdx.x;
    const long d = tid >> lg;
    const int  c = (int)(tid & ((1 << lg) - 1));
    if (d >= N) return;

    float acc[8] = {0.f, 0.f, 0.f, 0.f, 0.f, 0.f, 0.f, 0.f};
    const int start = rowptr[d];
    const int deg   = degi[d];
    for (int k = 0; k < deg; ++k) {
        const int   s  = csr_src[start + k];
        const float nm = csr_norm[start + k];
        bf16x8 v = *(const bf16x8*)(xwb + (long)s * cw + c * 8);
#pragma unroll
        for (int j = 0; j < 8; ++j) acc[j] += (float)v[j] * nm;
    }

    const float di = dinv[d], sl = di * di;
    bf16x8 vd = *(const bf16x8*)(xwb + d * cw + c * 8);
    const int col = colbase + c * 8;
    f32x4 o0, o1;
#pragma unroll
    for (int j = 0; j < 4; ++j) {
        float v0 = acc[j]     + (float)vd[j]     * sl + bias[col + j];
        float v1 = acc[4 + j] + (float)vd[4 + j] * sl + bias[col + 4 + j];
        o0[j] = (v0 >= 0.f) ? v0 : 0.01f * v0;
        o1[j] = (v1 >= 0.f) ? v1 : 0.01f * v1;
    }
    *(f32x4*)(out + d * 128 + col)     = o0;
    *(f32x4*)(out + d * 128 + col + 4) = o1;
}

// ---------------------------------------------------------------------------
// LP head
// ---------------------------------------------------------------------------
__global__ __launch_bounds__(256) void lp_kernel(
    const float* __restrict__ emb, const int* __restrict__ eli,
    const float* __restrict__ wpost, const float* __restrict__ bpost,
    float* __restrict__ logits, int EL)
{
    const int e = blockIdx.x * 256 + threadIdx.x;
    if (e >= EL) return;
    const long s = eli[e], d = eli[EL + e];
    float acc = 0.f;
#pragma unroll
    for (int c = 0; c < 32; ++c) {
        f32x4 vs = *(const f32x4*)(emb + s * 128 + c * 4);
        f32x4 vd = *(const f32x4*)(emb + d * 128 + c * 4);
        f32x4 w0 = *(const f32x4*)(wpost + c * 4);
        f32x4 w1 = *(const f32x4*)(wpost + 128 + c * 4);
#pragma unroll
        for (int i = 0; i < 4; ++i)
            acc += vs[i] * vd[i] * (w0[i] + w1[i]);
    }
    logits[e] = acc + bpost[0] + bpost[1];
}

// ---------------------------------------------------------------------------
extern "C" void kernel_launch(void* const* d_in, const int* in_sizes, int n_in,
                              void* d_out, int out_size, void* d_ws, size_t ws_size,
                              hipStream_t stream) {
    const float* x      = (const float*)d_in[0];
    const int*   ei     = (const int*)d_in[1];   // [2,E]: row0=src, row1=dst
    const int*   eli    = (const int*)d_in[2];
    const float* prev0  = (const float*)d_in[3];
    const float* prev1  = (const float*)d_in[4];
    const float* w_pre1 = (const float*)d_in[5];
    const float* b_pre1 = (const float*)d_in[6];
    const float* w_pre2 = (const float*)d_in[7];
    const float* b_pre2 = (const float*)d_in[8];
    const float* w_c1   = (const float*)d_in[9];
    const float* b_c1   = (const float*)d_in[10];
    const float* w_c2   = (const float*)d_in[11];
    const float* b_c2   = (const float*)d_in[12];
    const float* w_post = (const float*)d_in[13];
    const float* b_post = (const float*)d_in[14];
    const float* g1_wih = (const float*)d_in[15];
    const float* g1_whh = (const float*)d_in[16];
    const float* g1_bih = (const float*)d_in[17];
    const float* g1_bhh = (const float*)d_in[18];
    const float* g2_wih = (const float*)d_in[19];
    const float* g2_whh = (const float*)d_in[20];
    const float* g2_bih = (const float*)d_in[21];
    const float* g2_bhh = (const float*)d_in[22];

    const int N  = in_sizes[0] / 128;
    const int E  = in_sizes[1] / 2;
    const int EL = in_sizes[2] / 2;
    const long NH = (long)N * 128;

    // outputs (f32)
    float* out    = (float*)d_out;
    float* logits = out;
    float* emb0   = out + EL;
    float* emb1   = emb0 + NH;
    float* emb2   = emb1 + NH;

    // ---- workspace layout ----
    char* ws = (char*)d_ws;
    size_t p = 0;
    auto alloc = [&](size_t bytes) { size_t o = p; p = (p + bytes + 255) & ~(size_t)255; return o; };
    float* dinv    = (float*)(ws + alloc((size_t)N * 4));
    int*   degi    = (int*)  (ws + alloc((size_t)N * 4));
    int*   inc     = (int*)  (ws + alloc((size_t)N * 4));
    int*   rowptr  = (int*)  (ws + alloc((size_t)N * 4));
    int*   cursor  = (int*)  (ws + alloc((size_t)N * 4));
    int*   bsum    = (int*)  (ws + alloc(4096));
    bf16*  wb      = (bf16*) (ws + alloc((size_t)294912 * 2));
    int*   csr_src = (int*)  (ws + alloc((size_t)E * 4));
    float* csr_nrm = (float*)(ws + alloc((size_t)E * 4));
    const size_t fixed = p;
    bf16*  xwb     = (bf16*)(ws + fixed);

    // xw columns per pass, limited by remaining ws
    int cw = 128;
    while (cw > 16 && fixed + (size_t)N * cw * 2 > ws_size) cw >>= 1;
    const int lg = __builtin_ctz(cw >> 3);
    const int passes = 128 / cw;

    // bf16 weight copies (packed into wb)
    bf16* wb_pre1 = wb;                  // 32768
    bf16* wb_pre2 = wb_pre1 + 32768;     // 32768
    bf16* wb_c1   = wb_pre2 + 32768;     // 16384
    bf16* wb_c2   = wb_c1 + 16384;       // 16384
    bf16* wb_g1i  = wb_c2 + 16384;       // 49152
    bf16* wb_g1h  = wb_g1i + 49152;      // 49152
    bf16* wb_g2i  = wb_g1h + 49152;      // 49152
    bf16* wb_g2h  = wb_g2i + 49152;      // 49152

    const int gB = 256;
    const dim3 blk(gB);
    const int grid_rows64 = (N + 63) / 64;
    const int grid_gru    = (N + 63) / 64;   // 4 waves x 16 rows per block
    const int grid_E      = (E + gB - 1) / gB;
    const int grid_N      = (N + gB - 1) / gB;
    const int nb          = (N + 255) / 256;

    cvt_kernel<<<(32768 + 255) / 256, blk, 0, stream>>>(w_pre1, wb_pre1, 32768);
    cvt_kernel<<<(32768 + 255) / 256, blk, 0, stream>>>(w_pre2, wb_pre2, 32768);
    cvt_kernel<<<(16384 + 255) / 256, blk, 0, stream>>>(w_c1, wb_c1, 16384);
    cvt_kernel<<<(16384 + 255) / 256, blk, 0, stream>>>(w_c2, wb_c2, 16384);
    cvt_kernel<<<(49152 + 255) / 256, blk, 0, stream>>>(g1_wih, wb_g1i, 49152);
    cvt_kernel<<<(49152 + 255) / 256, blk, 0, stream>>>(g1_whh, wb_g1h, 49152);
    cvt_kernel<<<(49152 + 255) / 256, blk, 0, stream>>>(g2_wih, wb_g2i, 49152);
    cvt_kernel<<<(49152 + 255) / 256, blk, 0, stream>>>(g2_whh, wb_g2h, 49152);

    // ---- CSR build (once; reused by both convs) ----
    hipMemsetAsync(degi, 0, (size_t)N * 4, stream);
    deg_kernel<<<grid_E, blk, 0, stream>>>(ei + E, degi, E);
    dinv_kernel<<<grid_N, blk, 0, stream>>>(degi, dinv, N);
    scan1_kernel<<<nb, blk, 0, stream>>>(degi, inc, bsum, N);
    scan2_kernel<<<1, 512, 0, stream>>>(bsum, nb);
    scan3_kernel<<<nb, blk, 0, stream>>>(inc, degi, bsum, rowptr, N);
    hipMemsetAsync(cursor, 0, (size_t)N * 4, stream);
    fill_kernel<<<grid_E, blk, 0, stream>>>(ei, ei + E, rowptr, cursor, dinv, csr_src, csr_nrm, E);

    // ---- preprocess: H1 [N,256] across emb1+emb2 slots; H2 -> emb0 ----
    gemm_kernel<128, 256, true, true, float><<<grid_rows64, blk, 0, stream>>>(x, wb_pre1, b_pre1, emb1, N);
    gemm_kernel<256, 128, true, true, float><<<grid_rows64, blk, 0, stream>>>(emb1, wb_pre2, b_pre2, emb0, N);

    // GRU1: emb0 = gru(H2, prev0) (in place)
    gru_kernel<<<grid_gru, blk, 0, stream>>>(emb0, prev0, wb_g1i, wb_g1h, g1_bih, g1_bhh, emb0, N);

    // ---- conv via CSR gather ----
    const int grid_ga = (int)((((long)N << lg) + gB - 1) / gB);
    auto run_conv = [&](const float* hin, const bf16* wfull, const float* bc, float* aout) {
        for (int ps = 0; ps < passes; ++ps) {
            const int colbase = ps * cw;
            const bf16* wp = wfull + (size_t)colbase * 128;
            switch (cw) {
            case 128: gemm_kernel<128, 128, false, false, bf16><<<grid_rows64, blk, 0, stream>>>(hin, wp, nullptr, xwb, N); break;
            case 64:  gemm_kernel<128, 64,  false, false, bf16><<<grid_rows64, blk, 0, stream>>>(hin, wp, nullptr, xwb, N); break;
            case 32:  gemm_kernel<128, 32,  false, false, bf16><<<grid_rows64, blk, 0, stream>>>(hin, wp, nullptr, xwb, N); break;
            default:  gemm_kernel<128, 16,  false, false, bf16><<<grid_rows64, blk, 0, stream>>>(hin, wp, nullptr, xwb, N); break;
            }
            gather_kernel<<<grid_ga, blk, 0, stream>>>(xwb, rowptr, degi, csr_src, csr_nrm,
                                                       dinv, bc, aout, N, colbase, cw, lg);
        }
    };

    // conv1 -> emb1; GRU2 in place
    run_conv(emb0, wb_c1, b_c1, emb1);
    gru_kernel<<<grid_gru, blk, 0, stream>>>(emb1, prev0, wb_g1i, wb_g1h, g1_bih, g1_bhh, emb1, N);

    // conv2 -> emb2; GRU3 in place
    run_conv(emb1, wb_c2, b_c2, emb2);
    gru_kernel<<<grid_gru, blk, 0, stream>>>(emb2, prev1, wb_g2i, wb_g2h, g2_bih, g2_bhh, emb2, N);

    // LP head
    lp_kernel<<<(EL + gB - 1) / gB, blk, 0, stream>>>(emb2, eli, w_post, b_post, logits, EL);
}

// Round 6
// 690.140 us; speedup vs baseline: 7.6361x; 1.3954x over previous
//
#include <hip/hip_runtime.h>
#include <hip/hip_bf16.h>

// ---------------------------------------------------------------------------
// ROLAND GNN forward. Device buffers FLOAT32; matmuls bf16-MFMA, f32 accum.
// Outputs (concat, f32): logits[EL], emb0[N,128], emb1[N,128], emb2[N,128]
// Round 6: GRU with block-shared LDS weight tiles (kills L2 re-streaming).
// ---------------------------------------------------------------------------

typedef __bf16 bf16;
typedef __bf16 bf16x8 __attribute__((ext_vector_type(8)));
typedef float  f32x4  __attribute__((ext_vector_type(4)));

#define DEV __device__ __forceinline__

DEV f32x4 mfma16(bf16x8 a, bf16x8 b, f32x4 c) {
    return __builtin_amdgcn_mfma_f32_16x16x32_bf16(a, b, c, 0, 0, 0);
}

DEV bf16x8 load8_cvt(const float* p) {
    f32x4 lo = *(const f32x4*)p;
    f32x4 hi = *(const f32x4*)(p + 4);
    bf16x8 v;
    v[0] = (bf16)lo[0]; v[1] = (bf16)lo[1]; v[2] = (bf16)lo[2]; v[3] = (bf16)lo[3];
    v[4] = (bf16)hi[0]; v[5] = (bf16)hi[1]; v[6] = (bf16)hi[2]; v[7] = (bf16)hi[3];
    return v;
}

__global__ void cvt_kernel(const float* __restrict__ in, bf16* __restrict__ ob, int n) {
    const int i = blockIdx.x * 256 + threadIdx.x;
    if (i < n) ob[i] = (bf16)in[i];
}

// ---------------------------------------------------------------------------
// GEMM: C[M,Co] = act(A[M,Ci] @ W[Co,Ci]^T + bias). A f32, W bf16, out OT.
// ---------------------------------------------------------------------------
template<int Ci, int Co, bool ACT, bool BIAS, typename OT>
__global__ __launch_bounds__(256) void gemm_kernel(
    const float* __restrict__ A, const bf16* __restrict__ W,
    const float* __restrict__ bias, OT* __restrict__ C, int M)
{
    const int tid  = threadIdx.x;
    const int lane = tid & 63, w = tid >> 6;
    const int lr   = lane & 15, ko = lane >> 4;
    const int rbase = blockIdx.x * 64 + w * 16;

    long arow = rbase + lr; if (arow > M - 1) arow = M - 1;  // clamped rows never stored
    constexpr int KC = Ci / 32;
    constexpr int NT = Co / 16;

    bf16x8 a[KC];
#pragma unroll
    for (int kc = 0; kc < KC; ++kc)
        a[kc] = load8_cvt(A + arow * Ci + kc * 32 + ko * 8);

#pragma unroll
    for (int t = 0; t < NT; ++t) {
        f32x4 acc = {0.f, 0.f, 0.f, 0.f};
        const bf16* wp = W + (long)(t * 16 + lr) * Ci + ko * 8;
#pragma unroll
        for (int kc = 0; kc < KC; ++kc)
            acc = mfma16(a[kc], *(const bf16x8*)(wp + kc * 32), acc);

        const int col = t * 16 + lr;
        float bv = 0.f;
        if (BIAS) bv = bias[col];
#pragma unroll
        for (int j = 0; j < 4; ++j) {
            const int orow = rbase + ko * 4 + j;
            if (orow < M) {
                float v = acc[j] + bv;
                if (ACT) v = (v >= 0.f) ? v : 0.01f * v;
                C[(long)orow * Co + col] = (OT)v;
            }
        }
    }
}

// ---------------------------------------------------------------------------
// GRUCell with block-shared LDS weight tiles. Block = 4 waves x 32 rows.
// Per column-tile tc: stage 6x[16x128] bf16 weight tiles (24KB) into LDS
// (XOR-swizzled 16B chunks: cc ^= row&7 -> uniform 8 dwords/bank on both
// write and MFMA-read phases), then each wave computes 2 M-tiles of the
// r/z/n gates and blends -- register-local per lane (m89 C/D layout).
// Safe for out == x: A-frags are register-resident before any store; all
// waves stay in barriers (no early return).
// ---------------------------------------------------------------------------
__global__ __launch_bounds__(256) void gru_kernel(
    const float* x, const float* __restrict__ hp,
    const bf16* __restrict__ wih, const bf16* __restrict__ whh,
    const float* __restrict__ bih, const float* __restrict__ bhh,
    float* out, int N)
{
    __shared__ bf16 Lw[6][16][128];   // 24 KB

    const int tid  = threadIdx.x;
    const int lane = tid & 63, w = tid >> 6;
    const int lr   = lane & 15, ko = lane >> 4;
    const long rbase = (long)blockIdx.x * 128 + w * 32;

    // A fragments: 2 M-tiles x 4 k-chunks, x and hp
    bf16x8 ax[2][4], ah[2][4];
#pragma unroll
    for (int m = 0; m < 2; ++m) {
        long arow = rbase + m * 16 + lr; if (arow > N - 1) arow = N - 1;
#pragma unroll
        for (int kc = 0; kc < 4; ++kc) {
            ax[m][kc] = load8_cvt(x  + arow * 128 + kc * 32 + ko * 8);
            ah[m][kc] = load8_cvt(hp + arow * 128 + kc * 32 + ko * 8);
        }
    }

    for (int tc = 0; tc < 8; ++tc) {
        __syncthreads();   // previous tile's LDS reads complete
        // stage: 1536 16B chunks; slot (g,row,cc) <- global chunk (g,row,cc^(row&7))
#pragma unroll
        for (int i = 0; i < 6; ++i) {
            const int ch  = tid + 256 * i;
            const int g   = ch >> 8, rem = ch & 255;
            const int row = rem >> 4, cc = rem & 15;
            const int scc = cc ^ (row & 7);
            const bf16* wsrc = (g < 3 ? wih : whh)
                + (long)(((g % 3) * 128 + tc * 16 + row) * 128 + scc * 8);
            *(bf16x8*)(&Lw[g][row][cc * 8]) = *(const bf16x8*)wsrc;
        }
        __syncthreads();

        const int col = tc * 16 + lr;
        const float br = bih[col]       + bhh[col];
        const float bz = bih[128 + col] + bhh[128 + col];
        const float bi = bih[256 + col];
        const float bh = bhh[256 + col];

#pragma unroll
        for (int m = 0; m < 2; ++m) {
            f32x4 ar = {0.f, 0.f, 0.f, 0.f};
            f32x4 az = {0.f, 0.f, 0.f, 0.f};
            f32x4 ai = {0.f, 0.f, 0.f, 0.f};
            f32x4 ag = {0.f, 0.f, 0.f, 0.f};
#pragma unroll
            for (int kc = 0; kc < 4; ++kc) {
                const int cc = (kc * 4 + ko) ^ (lr & 7);
                bf16x8 wr_i = *(const bf16x8*)(&Lw[0][lr][cc * 8]);
                bf16x8 wz_i = *(const bf16x8*)(&Lw[1][lr][cc * 8]);
                bf16x8 wn_i = *(const bf16x8*)(&Lw[2][lr][cc * 8]);
                bf16x8 wr_h = *(const bf16x8*)(&Lw[3][lr][cc * 8]);
                bf16x8 wz_h = *(const bf16x8*)(&Lw[4][lr][cc * 8]);
                bf16x8 wn_h = *(const bf16x8*)(&Lw[5][lr][cc * 8]);
                ar = mfma16(ax[m][kc], wr_i, ar);
                ar = mfma16(ah[m][kc], wr_h, ar);
                az = mfma16(ax[m][kc], wz_i, az);
                az = mfma16(ah[m][kc], wz_h, az);
                ai = mfma16(ax[m][kc], wn_i, ai);
                ag = mfma16(ah[m][kc], wn_h, ag);
            }
#pragma unroll
            for (int j = 0; j < 4; ++j) {
                const long row = rbase + m * 16 + ko * 4 + j;
                if (row < N) {
                    const float r = 1.f / (1.f + __expf(-(ar[j] + br)));
                    const float z = 1.f / (1.f + __expf(-(az[j] + bz)));
                    const float pre = (ai[j] + bi) + r * (ag[j] + bh);
                    const float n = 1.f - 2.f / (1.f + __expf(2.f * pre));
                    out[row * 128 + col] = (1.f - z) * n + z * hp[row * 128 + col];
                }
            }
        }
    }
}

// ---------------------------------------------------------------------------
// CSR build
// ---------------------------------------------------------------------------
__global__ void deg_kernel(const int* __restrict__ dst, int* degi, int E) {
    const int e = blockIdx.x * 256 + threadIdx.x;
    if (e < E) atomicAdd(&degi[dst[e]], 1);
}

__global__ void dinv_kernel(const int* __restrict__ degi, float* __restrict__ dinv, int N) {
    const int i = blockIdx.x * 256 + threadIdx.x;
    if (i < N) dinv[i] = rsqrtf((float)degi[i] + 1.0f);   // +1 self loop
}

__global__ void scan1_kernel(const int* __restrict__ degi, int* __restrict__ inc,
                             int* __restrict__ bsum, int N) {
    __shared__ int s[256];
    const int i = blockIdx.x * 256 + threadIdx.x;
    s[threadIdx.x] = (i < N) ? degi[i] : 0;
    __syncthreads();
#pragma unroll
    for (int off = 1; off < 256; off <<= 1) {
        int t = (threadIdx.x >= off) ? s[threadIdx.x - off] : 0;
        __syncthreads();
        s[threadIdx.x] += t;
        __syncthreads();
    }
    if (i < N) inc[i] = s[threadIdx.x];
    if (threadIdx.x == 255) bsum[blockIdx.x] = s[255];
}

__global__ void scan2_kernel(int* bsum, int nb) {
    __shared__ int s[512];
    __shared__ int carry;
    if (threadIdx.x == 0) carry = 0;
    __syncthreads();
    for (int base = 0; base < nb; base += 512) {
        const int i = base + threadIdx.x;
        s[threadIdx.x] = (i < nb) ? bsum[i] : 0;
        __syncthreads();
#pragma unroll
        for (int off = 1; off < 512; off <<= 1) {
            int t = (threadIdx.x >= off) ? s[threadIdx.x - off] : 0;
            __syncthreads();
            s[threadIdx.x] += t;
            __syncthreads();
        }
        const int c = carry;
        if (i < nb) bsum[i] = s[threadIdx.x] + c;
        __syncthreads();
        if (threadIdx.x == 511) carry = c + s[511];
        __syncthreads();
    }
}

__global__ void scan3_kernel(const int* __restrict__ inc, const int* __restrict__ degi,
                             const int* __restrict__ bsum, int* __restrict__ rowptr, int N) {
    const int i = blockIdx.x * 256 + threadIdx.x;
    if (i >= N) return;
    const int prev = (blockIdx.x > 0) ? bsum[blockIdx.x - 1] : 0;
    rowptr[i] = prev + inc[i] - degi[i];   // exclusive prefix
}

__global__ void fill_kernel(const int* __restrict__ src, const int* __restrict__ dst,
                            const int* __restrict__ rowptr, int* cursor,
                            const float* __restrict__ dinv,
                            int* __restrict__ csr_src, float* __restrict__ csr_norm, int E) {
    const int e = blockIdx.x * 256 + threadIdx.x;
    if (e >= E) return;
    const int s = src[e], d = dst[e];
    const int pos = rowptr[d] + atomicAdd(&cursor[d], 1);
    csr_src[pos]  = s;
    csr_norm[pos] = dinv[s] * dinv[d];
}

// ---------------------------------------------------------------------------
// Fused gather + finalize: out[d, cols] = leaky(sum_in xwb[s]*nm + xwb[d]*di^2 + b)
// ---------------------------------------------------------------------------
__global__ __launch_bounds__(256) void gather_kernel(
    const bf16* __restrict__ xwb,            // [N, cw] bf16
    const int* __restrict__ rowptr, const int* __restrict__ degi,
    const int* __restrict__ csr_src, const float* __restrict__ csr_norm,
    const float* __restrict__ dinv, const float* __restrict__ bias,
    float* __restrict__ out, int N, int colbase, int cw, int lg)
{
    const long tid = (long)blockIdx.x * 256 + threadIdx.x;
    const long d = tid >> lg;
    const int  c = (int)(tid & ((1 << lg) - 1));
    if (d >= N) return;

    float acc[8] = {0.f, 0.f, 0.f, 0.f, 0.f, 0.f, 0.f, 0.f};
    const int start = rowptr[d];
    const int deg   = degi[d];
    for (int k = 0; k < deg; ++k) {
        const int   s  = csr_src[start + k];
        const float nm = csr_norm[start + k];
        bf16x8 v = *(const bf16x8*)(xwb + (long)s * cw + c * 8);
#pragma unroll
        for (int j = 0; j < 8; ++j) acc[j] += (float)v[j] * nm;
    }

    const float di = dinv[d], sl = di * di;
    bf16x8 vd = *(const bf16x8*)(xwb + d * cw + c * 8);
    const int col = colbase + c * 8;
    f32x4 o0, o1;
#pragma unroll
    for (int j = 0; j < 4; ++j) {
        float v0 = acc[j]     + (float)vd[j]     * sl + bias[col + j];
        float v1 = acc[4 + j] + (float)vd[4 + j] * sl + bias[col + 4 + j];
        o0[j] = (v0 >= 0.f) ? v0 : 0.01f * v0;
        o1[j] = (v1 >= 0.f) ? v1 : 0.01f * v1;
    }
    *(f32x4*)(out + d * 128 + col)     = o0;
    *(f32x4*)(out + d * 128 + col + 4) = o1;
}

// ---------------------------------------------------------------------------
// LP head
// ---------------------------------------------------------------------------
__global__ __launch_bounds__(256) void lp_kernel(
    const float* __restrict__ emb, const int* __restrict__ eli,
    const float* __restrict__ wpost, const float* __restrict__ bpost,
    float* __restrict__ logits, int EL)
{
    const int e = blockIdx.x * 256 + threadIdx.x;
    if (e >= EL) return;
    const long s = eli[e], d = eli[EL + e];
    float acc = 0.f;
#pragma unroll
    for (int c = 0; c < 32; ++c) {
        f32x4 vs = *(const f32x4*)(emb + s * 128 + c * 4);
        f32x4 vd = *(const f32x4*)(emb + d * 128 + c * 4);
        f32x4 w0 = *(const f32x4*)(wpost + c * 4);
        f32x4 w1 = *(const f32x4*)(wpost + 128 + c * 4);
#pragma unroll
        for (int i = 0; i < 4; ++i)
            acc += vs[i] * vd[i] * (w0[i] + w1[i]);
    }
    logits[e] = acc + bpost[0] + bpost[1];
}

// ---------------------------------------------------------------------------
extern "C" void kernel_launch(void* const* d_in, const int* in_sizes, int n_in,
                              void* d_out, int out_size, void* d_ws, size_t ws_size,
                              hipStream_t stream) {
    const float* x      = (const float*)d_in[0];
    const int*   ei     = (const int*)d_in[1];   // [2,E]: row0=src, row1=dst
    const int*   eli    = (const int*)d_in[2];
    const float* prev0  = (const float*)d_in[3];
    const float* prev1  = (const float*)d_in[4];
    const float* w_pre1 = (const float*)d_in[5];
    const float* b_pre1 = (const float*)d_in[6];
    const float* w_pre2 = (const float*)d_in[7];
    const float* b_pre2 = (const float*)d_in[8];
    const float* w_c1   = (const float*)d_in[9];
    const float* b_c1   = (const float*)d_in[10];
    const float* w_c2   = (const float*)d_in[11];
    const float* b_c2   = (const float*)d_in[12];
    const float* w_post = (const float*)d_in[13];
    const float* b_post = (const float*)d_in[14];
    const float* g1_wih = (const float*)d_in[15];
    const float* g1_whh = (const float*)d_in[16];
    const float* g1_bih = (const float*)d_in[17];
    const float* g1_bhh = (const float*)d_in[18];
    const float* g2_wih = (const float*)d_in[19];
    const float* g2_whh = (const float*)d_in[20];
    const float* g2_bih = (const float*)d_in[21];
    const float* g2_bhh = (const float*)d_in[22];

    const int N  = in_sizes[0] / 128;
    const int E  = in_sizes[1] / 2;
    const int EL = in_sizes[2] / 2;
    const long NH = (long)N * 128;

    // outputs (f32)
    float* out    = (float*)d_out;
    float* logits = out;
    float* emb0   = out + EL;
    float* emb1   = emb0 + NH;
    float* emb2   = emb1 + NH;

    // ---- workspace layout ----
    char* ws = (char*)d_ws;
    size_t p = 0;
    auto alloc = [&](size_t bytes) { size_t o = p; p = (p + bytes + 255) & ~(size_t)255; return o; };
    float* dinv    = (float*)(ws + alloc((size_t)N * 4));
    int*   degi    = (int*)  (ws + alloc((size_t)N * 4));
    int*   inc     = (int*)  (ws + alloc((size_t)N * 4));
    int*   rowptr  = (int*)  (ws + alloc((size_t)N * 4));
    int*   cursor  = (int*)  (ws + alloc((size_t)N * 4));
    int*   bsum    = (int*)  (ws + alloc(4096));
    bf16*  wb      = (bf16*) (ws + alloc((size_t)294912 * 2));
    int*   csr_src = (int*)  (ws + alloc((size_t)E * 4));
    float* csr_nrm = (float*)(ws + alloc((size_t)E * 4));
    const size_t fixed = p;
    bf16*  xwb     = (bf16*)(ws + fixed);

    // xw columns per pass, limited by remaining ws
    int cw = 128;
    while (cw > 16 && fixed + (size_t)N * cw * 2 > ws_size) cw >>= 1;
    const int lg = __builtin_ctz(cw >> 3);
    const int passes = 128 / cw;

    // bf16 weight copies (packed into wb)
    bf16* wb_pre1 = wb;                  // 32768
    bf16* wb_pre2 = wb_pre1 + 32768;     // 32768
    bf16* wb_c1   = wb_pre2 + 32768;     // 16384
    bf16* wb_c2   = wb_c1 + 16384;       // 16384
    bf16* wb_g1i  = wb_c2 + 16384;       // 49152
    bf16* wb_g1h  = wb_g1i + 49152;      // 49152
    bf16* wb_g2i  = wb_g1h + 49152;      // 49152
    bf16* wb_g2h  = wb_g2i + 49152;      // 49152

    const int gB = 256;
    const dim3 blk(gB);
    const int grid_rows64 = (N + 63) / 64;
    const int grid_gru    = (N + 127) / 128;   // 4 waves x 32 rows per block
    const int grid_E      = (E + gB - 1) / gB;
    const int grid_N      = (N + gB - 1) / gB;
    const int nb          = (N + 255) / 256;

    cvt_kernel<<<(32768 + 255) / 256, blk, 0, stream>>>(w_pre1, wb_pre1, 32768);
    cvt_kernel<<<(32768 + 255) / 256, blk, 0, stream>>>(w_pre2, wb_pre2, 32768);
    cvt_kernel<<<(16384 + 255) / 256, blk, 0, stream>>>(w_c1, wb_c1, 16384);
    cvt_kernel<<<(16384 + 255) / 256, blk, 0, stream>>>(w_c2, wb_c2, 16384);
    cvt_kernel<<<(49152 + 255) / 256, blk, 0, stream>>>(g1_wih, wb_g1i, 49152);
    cvt_kernel<<<(49152 + 255) / 256, blk, 0, stream>>>(g1_whh, wb_g1h, 49152);
    cvt_kernel<<<(49152 + 255) / 256, blk, 0, stream>>>(g2_wih, wb_g2i, 49152);
    cvt_kernel<<<(49152 + 255) / 256, blk, 0, stream>>>(g2_whh, wb_g2h, 49152);

    // ---- CSR build (once; reused by both convs) ----
    hipMemsetAsync(degi, 0, (size_t)N * 4, stream);
    deg_kernel<<<grid_E, blk, 0, stream>>>(ei + E, degi, E);
    dinv_kernel<<<grid_N, blk, 0, stream>>>(degi, dinv, N);
    scan1_kernel<<<nb, blk, 0, stream>>>(degi, inc, bsum, N);
    scan2_kernel<<<1, 512, 0, stream>>>(bsum, nb);
    scan3_kernel<<<nb, blk, 0, stream>>>(inc, degi, bsum, rowptr, N);
    hipMemsetAsync(cursor, 0, (size_t)N * 4, stream);
    fill_kernel<<<grid_E, blk, 0, stream>>>(ei, ei + E, rowptr, cursor, dinv, csr_src, csr_nrm, E);

    // ---- preprocess: H1 [N,256] across emb1+emb2 slots; H2 -> emb0 ----
    gemm_kernel<128, 256, true, true, float><<<grid_rows64, blk, 0, stream>>>(x, wb_pre1, b_pre1, emb1, N);
    gemm_kernel<256, 128, true, true, float><<<grid_rows64, blk, 0, stream>>>(emb1, wb_pre2, b_pre2, emb0, N);

    // GRU1: emb0 = gru(H2, prev0) (in place)
    gru_kernel<<<grid_gru, blk, 0, stream>>>(emb0, prev0, wb_g1i, wb_g1h, g1_bih, g1_bhh, emb0, N);

    // ---- conv via CSR gather ----
    const int grid_ga = (int)((((long)N << lg) + gB - 1) / gB);
    auto run_conv = [&](const float* hin, const bf16* wfull, const float* bc, float* aout) {
        for (int ps = 0; ps < passes; ++ps) {
            const int colbase = ps * cw;
            const bf16* wp = wfull + (size_t)colbase * 128;
            switch (cw) {
            case 128: gemm_kernel<128, 128, false, false, bf16><<<grid_rows64, blk, 0, stream>>>(hin, wp, nullptr, xwb, N); break;
            case 64:  gemm_kernel<128, 64,  false, false, bf16><<<grid_rows64, blk, 0, stream>>>(hin, wp, nullptr, xwb, N); break;
            case 32:  gemm_kernel<128, 32,  false, false, bf16><<<grid_rows64, blk, 0, stream>>>(hin, wp, nullptr, xwb, N); break;
            default:  gemm_kernel<128, 16,  false, false, bf16><<<grid_rows64, blk, 0, stream>>>(hin, wp, nullptr, xwb, N); break;
            }
            gather_kernel<<<grid_ga, blk, 0, stream>>>(xwb, rowptr, degi, csr_src, csr_nrm,
                                                       dinv, bc, aout, N, colbase, cw, lg);
        }
    };

    // conv1 -> emb1; GRU2 in place
    run_conv(emb0, wb_c1, b_c1, emb1);
    gru_kernel<<<grid_gru, blk, 0, stream>>>(emb1, prev0, wb_g1i, wb_g1h, g1_bih, g1_bhh, emb1, N);

    // conv2 -> emb2; GRU3 in place
    run_conv(emb1, wb_c2, b_c2, emb2);
    gru_kernel<<<grid_gru, blk, 0, stream>>>(emb2, prev1, wb_g2i, wb_g2h, g2_bih, g2_bhh, emb2, N);

    // LP head
    lp_kernel<<<(EL + gB - 1) / gB, blk, 0, stream>>>(emb2, eli, w_post, b_post, logits, EL);
}

// Round 7
// 668.434 us; speedup vs baseline: 7.8840x; 1.0325x over previous
//
#include <hip/hip_runtime.h>
#include <hip/hip_bf16.h>
#include <type_traits>

// ---------------------------------------------------------------------------
// ROLAND GNN forward. Buffers f32; matmuls bf16-MFMA, f32 accum.
// Outputs (concat, f32): logits[EL], emb0[N,128], emb1[N,128], emb2[N,128]
// Round 7: bf16 intermediates (H1, H2, conv outputs h) -- same rounding
// points as before (consumers cvt'd anyway), ~230MB less HBM traffic.
//   emb1 slot: H1b bf16[N,256] (dead after pre2) -> emb1 f32 (final)
//   emb2 slot: H2b bf16[N,128] -> h1b bf16[N,128] -> emb2 f32 (final)
//   ws: fixed tables | xwb bf16[N,cw] | h2b bf16[N,128] (if room, else
//       f32 fallback via emb2 in-place)
// ---------------------------------------------------------------------------

typedef __bf16 bf16;
typedef __bf16 bf16x8 __attribute__((ext_vector_type(8)));
typedef float  f32x4  __attribute__((ext_vector_type(4)));

#define DEV __device__ __forceinline__

DEV f32x4 mfma16(bf16x8 a, bf16x8 b, f32x4 c) {
    return __builtin_amdgcn_mfma_f32_16x16x32_bf16(a, b, c, 0, 0, 0);
}

DEV bf16x8 load_a8(const float* p) {
    f32x4 lo = *(const f32x4*)p;
    f32x4 hi = *(const f32x4*)(p + 4);
    bf16x8 v;
    v[0] = (bf16)lo[0]; v[1] = (bf16)lo[1]; v[2] = (bf16)lo[2]; v[3] = (bf16)lo[3];
    v[4] = (bf16)hi[0]; v[5] = (bf16)hi[1]; v[6] = (bf16)hi[2]; v[7] = (bf16)hi[3];
    return v;
}
DEV bf16x8 load_a8(const bf16* p) { return *(const bf16x8*)p; }

__global__ void cvt_kernel(const float* __restrict__ in, bf16* __restrict__ ob, int n) {
    const int i = blockIdx.x * 256 + threadIdx.x;
    if (i < n) ob[i] = (bf16)in[i];
}

// ---------------------------------------------------------------------------
// GEMM: C[M,Co] = act(A[M,Ci] @ W[Co,Ci]^T + bias). A f32|bf16, W bf16.
// MFMA 16x16x32 bf16; C/D layout (m89): col=lane&15, row=4*(lane>>4)+j.
// ---------------------------------------------------------------------------
template<int Ci, int Co, bool ACT, bool BIAS, typename AT, typename OT>
__global__ __launch_bounds__(256) void gemm_kernel(
    const AT* __restrict__ A, const bf16* __restrict__ W,
    const float* __restrict__ bias, OT* __restrict__ C, int M)
{
    const int tid  = threadIdx.x;
    const int lane = tid & 63, w = tid >> 6;
    const int lr   = lane & 15, ko = lane >> 4;
    const int rbase = blockIdx.x * 64 + w * 16;

    long arow = rbase + lr; if (arow > M - 1) arow = M - 1;  // clamped rows never stored
    constexpr int KC = Ci / 32;
    constexpr int NT = Co / 16;

    bf16x8 a[KC];
#pragma unroll
    for (int kc = 0; kc < KC; ++kc)
        a[kc] = load_a8(A + arow * Ci + kc * 32 + ko * 8);

#pragma unroll
    for (int t = 0; t < NT; ++t) {
        f32x4 acc = {0.f, 0.f, 0.f, 0.f};
        const bf16* wp = W + (long)(t * 16 + lr) * Ci + ko * 8;
#pragma unroll
        for (int kc = 0; kc < KC; ++kc)
            acc = mfma16(a[kc], *(const bf16x8*)(wp + kc * 32), acc);

        const int col = t * 16 + lr;
        float bv = 0.f;
        if (BIAS) bv = bias[col];
#pragma unroll
        for (int j = 0; j < 4; ++j) {
            const int orow = rbase + ko * 4 + j;
            if (orow < M) {
                float v = acc[j] + bv;
                if (ACT) v = (v >= 0.f) ? v : 0.01f * v;
                C[(long)orow * Co + col] = (OT)v;
            }
        }
    }
}

// ---------------------------------------------------------------------------
// GRUCell with block-shared LDS weight tiles. Block = 4 waves x 32 rows.
// x input f32 or bf16 (XT). Safe for out == x (f32 path): each wave reads
// only its own rows before storing them; no early return (uniform barriers).
// ---------------------------------------------------------------------------
template<typename XT>
__global__ __launch_bounds__(256) void gru_kernel(
    const XT* x, const float* __restrict__ hp,
    const bf16* __restrict__ wih, const bf16* __restrict__ whh,
    const float* __restrict__ bih, const float* __restrict__ bhh,
    float* out, int N)
{
    __shared__ bf16 Lw[6][16][128];   // 24 KB

    const int tid  = threadIdx.x;
    const int lane = tid & 63, w = tid >> 6;
    const int lr   = lane & 15, ko = lane >> 4;
    const long rbase = (long)blockIdx.x * 128 + w * 32;

    bf16x8 ax[2][4], ah[2][4];
#pragma unroll
    for (int m = 0; m < 2; ++m) {
        long arow = rbase + m * 16 + lr; if (arow > N - 1) arow = N - 1;
#pragma unroll
        for (int kc = 0; kc < 4; ++kc) {
            ax[m][kc] = load_a8(x  + arow * 128 + kc * 32 + ko * 8);
            ah[m][kc] = load_a8(hp + arow * 128 + kc * 32 + ko * 8);
        }
    }

    for (int tc = 0; tc < 8; ++tc) {
        __syncthreads();
#pragma unroll
        for (int i = 0; i < 6; ++i) {
            const int ch  = tid + 256 * i;
            const int g   = ch >> 8, rem = ch & 255;
            const int row = rem >> 4, cc = rem & 15;
            const int scc = cc ^ (row & 7);
            const bf16* wsrc = (g < 3 ? wih : whh)
                + (long)(((g % 3) * 128 + tc * 16 + row) * 128 + scc * 8);
            *(bf16x8*)(&Lw[g][row][cc * 8]) = *(const bf16x8*)wsrc;
        }
        __syncthreads();

        const int col = tc * 16 + lr;
        const float br = bih[col]       + bhh[col];
        const float bz = bih[128 + col] + bhh[128 + col];
        const float bi = bih[256 + col];
        const float bh = bhh[256 + col];

#pragma unroll
        for (int m = 0; m < 2; ++m) {
            f32x4 ar = {0.f, 0.f, 0.f, 0.f};
            f32x4 az = {0.f, 0.f, 0.f, 0.f};
            f32x4 ai = {0.f, 0.f, 0.f, 0.f};
            f32x4 ag = {0.f, 0.f, 0.f, 0.f};
#pragma unroll
            for (int kc = 0; kc < 4; ++kc) {
                const int cc = (kc * 4 + ko) ^ (lr & 7);
                bf16x8 wr_i = *(const bf16x8*)(&Lw[0][lr][cc * 8]);
                bf16x8 wz_i = *(const bf16x8*)(&Lw[1][lr][cc * 8]);
                bf16x8 wn_i = *(const bf16x8*)(&Lw[2][lr][cc * 8]);
                bf16x8 wr_h = *(const bf16x8*)(&Lw[3][lr][cc * 8]);
                bf16x8 wz_h = *(const bf16x8*)(&Lw[4][lr][cc * 8]);
                bf16x8 wn_h = *(const bf16x8*)(&Lw[5][lr][cc * 8]);
                ar = mfma16(ax[m][kc], wr_i, ar);
                ar = mfma16(ah[m][kc], wr_h, ar);
                az = mfma16(ax[m][kc], wz_i, az);
                az = mfma16(ah[m][kc], wz_h, az);
                ai = mfma16(ax[m][kc], wn_i, ai);
                ag = mfma16(ah[m][kc], wn_h, ag);
            }
#pragma unroll
            for (int j = 0; j < 4; ++j) {
                const long row = rbase + m * 16 + ko * 4 + j;
                if (row < N) {
                    const float r = 1.f / (1.f + __expf(-(ar[j] + br)));
                    const float z = 1.f / (1.f + __expf(-(az[j] + bz)));
                    const float pre = (ai[j] + bi) + r * (ag[j] + bh);
                    const float n = 1.f - 2.f / (1.f + __expf(2.f * pre));
                    out[row * 128 + col] = (1.f - z) * n + z * hp[row * 128 + col];
                }
            }
        }
    }
}

// ---------------------------------------------------------------------------
// CSR build
// ---------------------------------------------------------------------------
__global__ void deg_kernel(const int* __restrict__ dst, int* degi, int E) {
    const int e = blockIdx.x * 256 + threadIdx.x;
    if (e < E) atomicAdd(&degi[dst[e]], 1);
}

__global__ void dinv_kernel(const int* __restrict__ degi, float* __restrict__ dinv, int N) {
    const int i = blockIdx.x * 256 + threadIdx.x;
    if (i < N) dinv[i] = rsqrtf((float)degi[i] + 1.0f);   // +1 self loop
}

__global__ void scan1_kernel(const int* __restrict__ degi, int* __restrict__ inc,
                             int* __restrict__ bsum, int N) {
    __shared__ int s[256];
    const int i = blockIdx.x * 256 + threadIdx.x;
    s[threadIdx.x] = (i < N) ? degi[i] : 0;
    __syncthreads();
#pragma unroll
    for (int off = 1; off < 256; off <<= 1) {
        int t = (threadIdx.x >= off) ? s[threadIdx.x - off] : 0;
        __syncthreads();
        s[threadIdx.x] += t;
        __syncthreads();
    }
    if (i < N) inc[i] = s[threadIdx.x];
    if (threadIdx.x == 255) bsum[blockIdx.x] = s[255];
}

__global__ void scan2_kernel(int* bsum, int nb) {
    __shared__ int s[512];
    __shared__ int carry;
    if (threadIdx.x == 0) carry = 0;
    __syncthreads();
    for (int base = 0; base < nb; base += 512) {
        const int i = base + threadIdx.x;
        s[threadIdx.x] = (i < nb) ? bsum[i] : 0;
        __syncthreads();
#pragma unroll
        for (int off = 1; off < 512; off <<= 1) {
            int t = (threadIdx.x >= off) ? s[threadIdx.x - off] : 0;
            __syncthreads();
            s[threadIdx.x] += t;
            __syncthreads();
        }
        const int c = carry;
        if (i < nb) bsum[i] = s[threadIdx.x] + c;
        __syncthreads();
        if (threadIdx.x == 511) carry = c + s[511];
        __syncthreads();
    }
}

__global__ void scan3_kernel(const int* __restrict__ inc, const int* __restrict__ degi,
                             const int* __restrict__ bsum, int* __restrict__ rowptr, int N) {
    const int i = blockIdx.x * 256 + threadIdx.x;
    if (i >= N) return;
    const int prev = (blockIdx.x > 0) ? bsum[blockIdx.x - 1] : 0;
    rowptr[i] = prev + inc[i] - degi[i];   // exclusive prefix
}

__global__ void fill_kernel(const int* __restrict__ src, const int* __restrict__ dst,
                            const int* __restrict__ rowptr, int* cursor,
                            const float* __restrict__ dinv,
                            int* __restrict__ csr_src, float* __restrict__ csr_norm, int E) {
    const int e = blockIdx.x * 256 + threadIdx.x;
    if (e >= E) return;
    const int s = src[e], d = dst[e];
    const int pos = rowptr[d] + atomicAdd(&cursor[d], 1);
    csr_src[pos]  = s;
    csr_norm[pos] = dinv[s] * dinv[d];
}

// ---------------------------------------------------------------------------
// Fused gather + finalize: out[d, cols] = leaky(sum_in xwb[s]*nm + xwb[d]*di^2 + b)
// OT = bf16 (compact intermediate) or float.
// ---------------------------------------------------------------------------
template<typename OT>
__global__ __launch_bounds__(256) void gather_kernel(
    const bf16* __restrict__ xwb,            // [N, cw] bf16
    const int* __restrict__ rowptr, const int* __restrict__ degi,
    const int* __restrict__ csr_src, const float* __restrict__ csr_norm,
    const float* __restrict__ dinv, const float* __restrict__ bias,
    OT* __restrict__ out, int N, int colbase, int cw, int lg)
{
    const long tid = (long)blockIdx.x * 256 + threadIdx.x;
    const long d = tid >> lg;
    const int  c = (int)(tid & ((1 << lg) - 1));
    if (d >= N) return;

    float acc[8] = {0.f, 0.f, 0.f, 0.f, 0.f, 0.f, 0.f, 0.f};
    const int start = rowptr[d];
    const int deg   = degi[d];
    for (int k = 0; k < deg; ++k) {
        const int   s  = csr_src[start + k];
        const float nm = csr_norm[start + k];
        bf16x8 v = *(const bf16x8*)(xwb + (long)s * cw + c * 8);
#pragma unroll
        for (int j = 0; j < 8; ++j) acc[j] += (float)v[j] * nm;
    }

    const float di = dinv[d], sl = di * di;
    bf16x8 vd = *(const bf16x8*)(xwb + d * cw + c * 8);
    const int col = colbase + c * 8;
    float v[8];
#pragma unroll
    for (int j = 0; j < 8; ++j) {
        float t = acc[j] + (float)vd[j] * sl + bias[col + j];
        v[j] = (t >= 0.f) ? t : 0.01f * t;
    }
    if constexpr (std::is_same<OT, bf16>::value) {
        bf16x8 o;
#pragma unroll
        for (int j = 0; j < 8; ++j) o[j] = (bf16)v[j];
        *(bf16x8*)(out + d * 128 + col) = o;
    } else {
        f32x4 o0, o1;
#pragma unroll
        for (int j = 0; j < 4; ++j) { o0[j] = v[j]; o1[j] = v[4 + j]; }
        *(f32x4*)(out + d * 128 + col)     = o0;
        *(f32x4*)(out + d * 128 + col + 4) = o1;
    }
}

// ---------------------------------------------------------------------------
// LP head
// ---------------------------------------------------------------------------
__global__ __launch_bounds__(256) void lp_kernel(
    const float* __restrict__ emb, const int* __restrict__ eli,
    const float* __restrict__ wpost, const float* __restrict__ bpost,
    float* __restrict__ logits, int EL)
{
    const int e = blockIdx.x * 256 + threadIdx.x;
    if (e >= EL) return;
    const long s = eli[e], d = eli[EL + e];
    float acc = 0.f;
#pragma unroll
    for (int c = 0; c < 32; ++c) {
        f32x4 vs = *(const f32x4*)(emb + s * 128 + c * 4);
        f32x4 vd = *(const f32x4*)(emb + d * 128 + c * 4);
        f32x4 w0 = *(const f32x4*)(wpost + c * 4);
        f32x4 w1 = *(const f32x4*)(wpost + 128 + c * 4);
#pragma unroll
        for (int i = 0; i < 4; ++i)
            acc += vs[i] * vd[i] * (w0[i] + w1[i]);
    }
    logits[e] = acc + bpost[0] + bpost[1];
}

// ---------------------------------------------------------------------------
extern "C" void kernel_launch(void* const* d_in, const int* in_sizes, int n_in,
                              void* d_out, int out_size, void* d_ws, size_t ws_size,
                              hipStream_t stream) {
    const float* x      = (const float*)d_in[0];
    const int*   ei     = (const int*)d_in[1];   // [2,E]: row0=src, row1=dst
    const int*   eli    = (const int*)d_in[2];
    const float* prev0  = (const float*)d_in[3];
    const float* prev1  = (const float*)d_in[4];
    const float* w_pre1 = (const float*)d_in[5];
    const float* b_pre1 = (const float*)d_in[6];
    const float* w_pre2 = (const float*)d_in[7];
    const float* b_pre2 = (const float*)d_in[8];
    const float* w_c1   = (const float*)d_in[9];
    const float* b_c1   = (const float*)d_in[10];
    const float* w_c2   = (const float*)d_in[11];
    const float* b_c2   = (const float*)d_in[12];
    const float* w_post = (const float*)d_in[13];
    const float* b_post = (const float*)d_in[14];
    const float* g1_wih = (const float*)d_in[15];
    const float* g1_whh = (const float*)d_in[16];
    const float* g1_bih = (const float*)d_in[17];
    const float* g1_bhh = (const float*)d_in[18];
    const float* g2_wih = (const float*)d_in[19];
    const float* g2_whh = (const float*)d_in[20];
    const float* g2_bih = (const float*)d_in[21];
    const float* g2_bhh = (const float*)d_in[22];

    const int N  = in_sizes[0] / 128;
    const int E  = in_sizes[1] / 2;
    const int EL = in_sizes[2] / 2;
    const long NH = (long)N * 128;

    // outputs (f32)
    float* out    = (float*)d_out;
    float* logits = out;
    float* emb0   = out + EL;
    float* emb1   = emb0 + NH;
    float* emb2   = emb1 + NH;

    // bf16 intermediates living in currently-dead output slots
    bf16* H1b = (bf16*)emb1;   // [N,256] bf16 == 51.2MB == emb1 slot exactly
    bf16* H2b = (bf16*)emb2;   // [N,128] bf16 (first half of emb2 slot)
    bf16* h1b = (bf16*)emb2;   // reuses emb2 slot after H2b is dead

    // ---- workspace layout ----
    char* ws = (char*)d_ws;
    size_t p = 0;
    auto alloc = [&](size_t bytes) { size_t o = p; p = (p + bytes + 255) & ~(size_t)255; return o; };
    float* dinv    = (float*)(ws + alloc((size_t)N * 4));
    int*   degi    = (int*)  (ws + alloc((size_t)N * 4));
    int*   inc     = (int*)  (ws + alloc((size_t)N * 4));
    int*   rowptr  = (int*)  (ws + alloc((size_t)N * 4));
    int*   cursor  = (int*)  (ws + alloc((size_t)N * 4));
    int*   bsum    = (int*)  (ws + alloc(4096));
    bf16*  wb      = (bf16*) (ws + alloc((size_t)294912 * 2));
    int*   csr_src = (int*)  (ws + alloc((size_t)E * 4));
    float* csr_nrm = (float*)(ws + alloc((size_t)E * 4));
    const size_t fixed = p;
    bf16*  xwb     = (bf16*)(ws + fixed);

    // xw columns per pass, limited by remaining ws
    int cw = 128;
    while (cw > 16 && fixed + (size_t)N * cw * 2 > ws_size) cw >>= 1;
    const int lg = __builtin_ctz(cw >> 3);
    const int passes = 128 / cw;

    // h2b (conv2 bf16 output) in ws if it fits after a full-width xwb
    const bool big_ws = (cw == 128) &&
        (ws_size >= fixed + (size_t)N * 128 * 2 + (size_t)N * 128 * 2);
    bf16* h2b = big_ws ? (bf16*)(ws + fixed + (size_t)N * 128 * 2) : nullptr;

    // bf16 weight copies (packed into wb)
    bf16* wb_pre1 = wb;                  // 32768
    bf16* wb_pre2 = wb_pre1 + 32768;     // 32768
    bf16* wb_c1   = wb_pre2 + 32768;     // 16384
    bf16* wb_c2   = wb_c1 + 16384;       // 16384
    bf16* wb_g1i  = wb_c2 + 16384;       // 49152
    bf16* wb_g1h  = wb_g1i + 49152;      // 49152
    bf16* wb_g2i  = wb_g1h + 49152;      // 49152
    bf16* wb_g2h  = wb_g2i + 49152;      // 49152

    const int gB = 256;
    const dim3 blk(gB);
    const int grid_rows64 = (N + 63) / 64;
    const int grid_gru    = (N + 127) / 128;   // 4 waves x 32 rows per block
    const int grid_E      = (E + gB - 1) / gB;
    const int grid_N      = (N + gB - 1) / gB;
    const int nb          = (N + 255) / 256;

    cvt_kernel<<<(32768 + 255) / 256, blk, 0, stream>>>(w_pre1, wb_pre1, 32768);
    cvt_kernel<<<(32768 + 255) / 256, blk, 0, stream>>>(w_pre2, wb_pre2, 32768);
    cvt_kernel<<<(16384 + 255) / 256, blk, 0, stream>>>(w_c1, wb_c1, 16384);
    cvt_kernel<<<(16384 + 255) / 256, blk, 0, stream>>>(w_c2, wb_c2, 16384);
    cvt_kernel<<<(49152 + 255) / 256, blk, 0, stream>>>(g1_wih, wb_g1i, 49152);
    cvt_kernel<<<(49152 + 255) / 256, blk, 0, stream>>>(g1_whh, wb_g1h, 49152);
    cvt_kernel<<<(49152 + 255) / 256, blk, 0, stream>>>(g2_wih, wb_g2i, 49152);
    cvt_kernel<<<(49152 + 255) / 256, blk, 0, stream>>>(g2_whh, wb_g2h, 49152);

    // ---- CSR build (once; reused by both convs) ----
    hipMemsetAsync(degi, 0, (size_t)N * 4, stream);
    deg_kernel<<<grid_E, blk, 0, stream>>>(ei + E, degi, E);
    dinv_kernel<<<grid_N, blk, 0, stream>>>(degi, dinv, N);
    scan1_kernel<<<nb, blk, 0, stream>>>(degi, inc, bsum, N);
    scan2_kernel<<<1, 512, 0, stream>>>(bsum, nb);
    scan3_kernel<<<nb, blk, 0, stream>>>(inc, degi, bsum, rowptr, N);
    hipMemsetAsync(cursor, 0, (size_t)N * 4, stream);
    fill_kernel<<<grid_E, blk, 0, stream>>>(ei, ei + E, rowptr, cursor, dinv, csr_src, csr_nrm, E);

    // ---- preprocess: x -> H1b (bf16, emb1 slot) -> H2b (bf16, emb2 slot) ----
    gemm_kernel<128, 256, true, true, float, bf16><<<grid_rows64, blk, 0, stream>>>(x, wb_pre1, b_pre1, H1b, N);
    gemm_kernel<256, 128, true, true, bf16,  bf16><<<grid_rows64, blk, 0, stream>>>(H1b, wb_pre2, b_pre2, H2b, N);

    // GRU1: emb0 = gru(H2b, prev0)
    gru_kernel<bf16><<<grid_gru, blk, 0, stream>>>(H2b, prev0, wb_g1i, wb_g1h, g1_bih, g1_bhh, emb0, N);

    // ---- conv via CSR gather ----
    const int grid_ga = (int)((((long)N << lg) + gB - 1) / gB);
    auto run_gemm = [&](const float* hin, const bf16* wp) {
        switch (cw) {
        case 128: gemm_kernel<128, 128, false, false, float, bf16><<<grid_rows64, blk, 0, stream>>>(hin, wp, nullptr, xwb, N); break;
        case 64:  gemm_kernel<128, 64,  false, false, float, bf16><<<grid_rows64, blk, 0, stream>>>(hin, wp, nullptr, xwb, N); break;
        case 32:  gemm_kernel<128, 32,  false, false, float, bf16><<<grid_rows64, blk, 0, stream>>>(hin, wp, nullptr, xwb, N); break;
        default:  gemm_kernel<128, 16,  false, false, float, bf16><<<grid_rows64, blk, 0, stream>>>(hin, wp, nullptr, xwb, N); break;
        }
    };

    // conv1: emb0 -> xwb -> h1b (bf16, emb2 slot); GRU2 -> emb1 (slot now free)
    for (int ps = 0; ps < passes; ++ps) {
        run_gemm(emb0, wb_c1 + (size_t)(ps * cw) * 128);
        gather_kernel<bf16><<<grid_ga, blk, 0, stream>>>(xwb, rowptr, degi, csr_src, csr_nrm,
                                                         dinv, b_c1, h1b, N, ps * cw, cw, lg);
    }
    gru_kernel<bf16><<<grid_gru, blk, 0, stream>>>(h1b, prev0, wb_g1i, wb_g1h, g1_bih, g1_bhh, emb1, N);

    // conv2: emb1 -> xwb -> h2b (ws) or emb2 f32 (fallback); GRU3 -> emb2
    for (int ps = 0; ps < passes; ++ps) {
        run_gemm(emb1, wb_c2 + (size_t)(ps * cw) * 128);
        if (big_ws)
            gather_kernel<bf16><<<grid_ga, blk, 0, stream>>>(xwb, rowptr, degi, csr_src, csr_nrm,
                                                             dinv, b_c2, h2b, N, ps * cw, cw, lg);
        else
            gather_kernel<float><<<grid_ga, blk, 0, stream>>>(xwb, rowptr, degi, csr_src, csr_nrm,
                                                              dinv, b_c2, emb2, N, ps * cw, cw, lg);
    }
    if (big_ws)
        gru_kernel<bf16><<<grid_gru, blk, 0, stream>>>(h2b, prev1, wb_g2i, wb_g2h, g2_bih, g2_bhh, emb2, N);
    else
        gru_kernel<float><<<grid_gru, blk, 0, stream>>>(emb2, prev1, wb_g2i, wb_g2h, g2_bih, g2_bhh, emb2, N);

    // LP head
    lp_kernel<<<(EL + gB - 1) / gB, blk, 0, stream>>>(emb2, eli, w_post, b_post, logits, EL);
}

// Round 8
// 588.276 us; speedup vs baseline: 8.9583x; 1.1363x over previous
//
#include <hip/hip_runtime.h>
#include <hip/hip_bf16.h>
#include <type_traits>

// ---------------------------------------------------------------------------
// ROLAND GNN forward. Buffers f32; matmuls bf16-MFMA, f32 accum.
// Outputs (concat, f32): logits[EL], emb0[N,128], emb1[N,128], emb2[N,128]
// Round 8: GRU 64-row blocks (grid 2x, occupancy-driven latency hiding);
//          gather dual-chain edge pipelining.
// ---------------------------------------------------------------------------

typedef __bf16 bf16;
typedef __bf16 bf16x8 __attribute__((ext_vector_type(8)));
typedef float  f32x4  __attribute__((ext_vector_type(4)));

#define DEV __device__ __forceinline__

DEV f32x4 mfma16(bf16x8 a, bf16x8 b, f32x4 c) {
    return __builtin_amdgcn_mfma_f32_16x16x32_bf16(a, b, c, 0, 0, 0);
}

DEV bf16x8 load_a8(const float* p) {
    f32x4 lo = *(const f32x4*)p;
    f32x4 hi = *(const f32x4*)(p + 4);
    bf16x8 v;
    v[0] = (bf16)lo[0]; v[1] = (bf16)lo[1]; v[2] = (bf16)lo[2]; v[3] = (bf16)lo[3];
    v[4] = (bf16)hi[0]; v[5] = (bf16)hi[1]; v[6] = (bf16)hi[2]; v[7] = (bf16)hi[3];
    return v;
}
DEV bf16x8 load_a8(const bf16* p) { return *(const bf16x8*)p; }

__global__ void cvt_kernel(const float* __restrict__ in, bf16* __restrict__ ob, int n) {
    const int i = blockIdx.x * 256 + threadIdx.x;
    if (i < n) ob[i] = (bf16)in[i];
}

// ---------------------------------------------------------------------------
// GEMM: C[M,Co] = act(A[M,Ci] @ W[Co,Ci]^T + bias). A f32|bf16, W bf16.
// MFMA 16x16x32 bf16; C/D layout (m89): col=lane&15, row=4*(lane>>4)+j.
// ---------------------------------------------------------------------------
template<int Ci, int Co, bool ACT, bool BIAS, typename AT, typename OT>
__global__ __launch_bounds__(256) void gemm_kernel(
    const AT* __restrict__ A, const bf16* __restrict__ W,
    const float* __restrict__ bias, OT* __restrict__ C, int M)
{
    const int tid  = threadIdx.x;
    const int lane = tid & 63, w = tid >> 6;
    const int lr   = lane & 15, ko = lane >> 4;
    const int rbase = blockIdx.x * 64 + w * 16;

    long arow = rbase + lr; if (arow > M - 1) arow = M - 1;  // clamped rows never stored
    constexpr int KC = Ci / 32;
    constexpr int NT = Co / 16;

    bf16x8 a[KC];
#pragma unroll
    for (int kc = 0; kc < KC; ++kc)
        a[kc] = load_a8(A + arow * Ci + kc * 32 + ko * 8);

#pragma unroll
    for (int t = 0; t < NT; ++t) {
        f32x4 acc = {0.f, 0.f, 0.f, 0.f};
        const bf16* wp = W + (long)(t * 16 + lr) * Ci + ko * 8;
#pragma unroll
        for (int kc = 0; kc < KC; ++kc)
            acc = mfma16(a[kc], *(const bf16x8*)(wp + kc * 32), acc);

        const int col = t * 16 + lr;
        float bv = 0.f;
        if (BIAS) bv = bias[col];
#pragma unroll
        for (int j = 0; j < 4; ++j) {
            const int orow = rbase + ko * 4 + j;
            if (orow < M) {
                float v = acc[j] + bv;
                if (ACT) v = (v >= 0.f) ? v : 0.01f * v;
                C[(long)orow * Co + col] = (OT)v;
            }
        }
    }
}

// ---------------------------------------------------------------------------
// GRUCell, 64-row blocks: 4 waves x 16 rows (1 M-tile/wave). Per column-tile
// tc the block stages 6x[16x128] weight tiles (24KB, XOR-swizzled) into LDS;
// each wave computes r/z/n for its 16 rows and blends. Grid = N/64 blocks ->
// ~6 blocks/CU interleave to hide stage latency and barriers.
// Safe for out == x (f32 path): all A-frag reads precede the first barrier,
// hence all stores; clamp row N-1 is owned by the same last block.
// ---------------------------------------------------------------------------
template<typename XT>
__global__ __launch_bounds__(256) void gru_kernel(
    const XT* x, const float* __restrict__ hp,
    const bf16* __restrict__ wih, const bf16* __restrict__ whh,
    const float* __restrict__ bih, const float* __restrict__ bhh,
    float* out, int N)
{
    __shared__ bf16 Lw[6][16][128];   // 24 KB

    const int tid  = threadIdx.x;
    const int lane = tid & 63, w = tid >> 6;
    const int lr   = lane & 15, ko = lane >> 4;
    const long rbase = (long)blockIdx.x * 64 + w * 16;

    long arow = rbase + lr; if (arow > N - 1) arow = N - 1;
    bf16x8 ax[4], ah[4];
#pragma unroll
    for (int kc = 0; kc < 4; ++kc) {
        ax[kc] = load_a8(x  + arow * 128 + kc * 32 + ko * 8);
        ah[kc] = load_a8(hp + arow * 128 + kc * 32 + ko * 8);
    }

    for (int tc = 0; tc < 8; ++tc) {
        __syncthreads();
#pragma unroll
        for (int i = 0; i < 6; ++i) {
            const int ch  = tid + 256 * i;
            const int g   = ch >> 8, rem = ch & 255;
            const int row = rem >> 4, cc = rem & 15;
            const int scc = cc ^ (row & 7);
            const bf16* wsrc = (g < 3 ? wih : whh)
                + (long)(((g % 3) * 128 + tc * 16 + row) * 128 + scc * 8);
            *(bf16x8*)(&Lw[g][row][cc * 8]) = *(const bf16x8*)wsrc;
        }
        __syncthreads();

        const int col = tc * 16 + lr;
        const float br = bih[col]       + bhh[col];
        const float bz = bih[128 + col] + bhh[128 + col];
        const float bi = bih[256 + col];
        const float bh = bhh[256 + col];

        f32x4 ar = {0.f, 0.f, 0.f, 0.f};
        f32x4 az = {0.f, 0.f, 0.f, 0.f};
        f32x4 ai = {0.f, 0.f, 0.f, 0.f};
        f32x4 ag = {0.f, 0.f, 0.f, 0.f};
#pragma unroll
        for (int kc = 0; kc < 4; ++kc) {
            const int cc = (kc * 4 + ko) ^ (lr & 7);
            bf16x8 wr_i = *(const bf16x8*)(&Lw[0][lr][cc * 8]);
            bf16x8 wz_i = *(const bf16x8*)(&Lw[1][lr][cc * 8]);
            bf16x8 wn_i = *(const bf16x8*)(&Lw[2][lr][cc * 8]);
            bf16x8 wr_h = *(const bf16x8*)(&Lw[3][lr][cc * 8]);
            bf16x8 wz_h = *(const bf16x8*)(&Lw[4][lr][cc * 8]);
            bf16x8 wn_h = *(const bf16x8*)(&Lw[5][lr][cc * 8]);
            ar = mfma16(ax[kc], wr_i, ar);
            ar = mfma16(ah[kc], wr_h, ar);
            az = mfma16(ax[kc], wz_i, az);
            az = mfma16(ah[kc], wz_h, az);
            ai = mfma16(ax[kc], wn_i, ai);
            ag = mfma16(ah[kc], wn_h, ag);
        }
#pragma unroll
        for (int j = 0; j < 4; ++j) {
            const long row = rbase + ko * 4 + j;
            if (row < N) {
                const float r = 1.f / (1.f + __expf(-(ar[j] + br)));
                const float z = 1.f / (1.f + __expf(-(az[j] + bz)));
                const float pre = (ai[j] + bi) + r * (ag[j] + bh);
                const float n = 1.f - 2.f / (1.f + __expf(2.f * pre));
                out[row * 128 + col] = (1.f - z) * n + z * hp[row * 128 + col];
            }
        }
    }
}

// ---------------------------------------------------------------------------
// CSR build
// ---------------------------------------------------------------------------
__global__ void deg_kernel(const int* __restrict__ dst, int* degi, int E) {
    const int e = blockIdx.x * 256 + threadIdx.x;
    if (e < E) atomicAdd(&degi[dst[e]], 1);
}

__global__ void dinv_kernel(const int* __restrict__ degi, float* __restrict__ dinv, int N) {
    const int i = blockIdx.x * 256 + threadIdx.x;
    if (i < N) dinv[i] = rsqrtf((float)degi[i] + 1.0f);   // +1 self loop
}

__global__ void scan1_kernel(const int* __restrict__ degi, int* __restrict__ inc,
                             int* __restrict__ bsum, int N) {
    __shared__ int s[256];
    const int i = blockIdx.x * 256 + threadIdx.x;
    s[threadIdx.x] = (i < N) ? degi[i] : 0;
    __syncthreads();
#pragma unroll
    for (int off = 1; off < 256; off <<= 1) {
        int t = (threadIdx.x >= off) ? s[threadIdx.x - off] : 0;
        __syncthreads();
        s[threadIdx.x] += t;
        __syncthreads();
    }
    if (i < N) inc[i] = s[threadIdx.x];
    if (threadIdx.x == 255) bsum[blockIdx.x] = s[255];
}

__global__ void scan2_kernel(int* bsum, int nb) {
    __shared__ int s[512];
    __shared__ int carry;
    if (threadIdx.x == 0) carry = 0;
    __syncthreads();
    for (int base = 0; base < nb; base += 512) {
        const int i = base + threadIdx.x;
        s[threadIdx.x] = (i < nb) ? bsum[i] : 0;
        __syncthreads();
#pragma unroll
        for (int off = 1; off < 512; off <<= 1) {
            int t = (threadIdx.x >= off) ? s[threadIdx.x - off] : 0;
            __syncthreads();
            s[threadIdx.x] += t;
            __syncthreads();
        }
        const int c = carry;
        if (i < nb) bsum[i] = s[threadIdx.x] + c;
        __syncthreads();
        if (threadIdx.x == 511) carry = c + s[511];
        __syncthreads();
    }
}

__global__ void scan3_kernel(const int* __restrict__ inc, const int* __restrict__ degi,
                             const int* __restrict__ bsum, int* __restrict__ rowptr, int N) {
    const int i = blockIdx.x * 256 + threadIdx.x;
    if (i >= N) return;
    const int prev = (blockIdx.x > 0) ? bsum[blockIdx.x - 1] : 0;
    rowptr[i] = prev + inc[i] - degi[i];   // exclusive prefix
}

__global__ void fill_kernel(const int* __restrict__ src, const int* __restrict__ dst,
                            const int* __restrict__ rowptr, int* cursor,
                            const float* __restrict__ dinv,
                            int* __restrict__ csr_src, float* __restrict__ csr_norm, int E) {
    const int e = blockIdx.x * 256 + threadIdx.x;
    if (e >= E) return;
    const int s = src[e], d = dst[e];
    const int pos = rowptr[d] + atomicAdd(&cursor[d], 1);
    csr_src[pos]  = s;
    csr_norm[pos] = dinv[s] * dinv[d];
}

// ---------------------------------------------------------------------------
// Fused gather + finalize, dual-chain edge pipeline:
// out[d, cols] = leaky(sum_in xwb[s]*nm + xwb[d]*di^2 + b)
// ---------------------------------------------------------------------------
template<typename OT>
__global__ __launch_bounds__(256) void gather_kernel(
    const bf16* __restrict__ xwb,            // [N, cw] bf16
    const int* __restrict__ rowptr, const int* __restrict__ degi,
    const int* __restrict__ csr_src, const float* __restrict__ csr_norm,
    const float* __restrict__ dinv, const float* __restrict__ bias,
    OT* __restrict__ out, int N, int colbase, int cw, int lg)
{
    const long tid = (long)blockIdx.x * 256 + threadIdx.x;
    const long d = tid >> lg;
    const int  c = (int)(tid & ((1 << lg) - 1));
    if (d >= N) return;

    const int start = rowptr[d];
    const int deg   = degi[d];
    const int h     = deg >> 1;
    const bf16* xb  = xwb + c * 8;

    float acca[8] = {0.f, 0.f, 0.f, 0.f, 0.f, 0.f, 0.f, 0.f};
    float accb[8] = {0.f, 0.f, 0.f, 0.f, 0.f, 0.f, 0.f, 0.f};
    for (int k = 0; k < h; ++k) {
        const int   sa = csr_src[start + k];
        const int   sb = csr_src[start + h + k];
        const float na = csr_norm[start + k];
        const float nb_ = csr_norm[start + h + k];
        bf16x8 va = *(const bf16x8*)(xb + (long)sa * cw);
        bf16x8 vb = *(const bf16x8*)(xb + (long)sb * cw);
#pragma unroll
        for (int j = 0; j < 8; ++j) {
            acca[j] += (float)va[j] * na;
            accb[j] += (float)vb[j] * nb_;
        }
    }
    if (deg & 1) {
        const int   s  = csr_src[start + deg - 1];
        const float nm = csr_norm[start + deg - 1];
        bf16x8 v = *(const bf16x8*)(xb + (long)s * cw);
#pragma unroll
        for (int j = 0; j < 8; ++j) acca[j] += (float)v[j] * nm;
    }

    const float di = dinv[d], sl = di * di;
    bf16x8 vd = *(const bf16x8*)(xb + d * cw);
    const int col = colbase + c * 8;
    float v[8];
#pragma unroll
    for (int j = 0; j < 8; ++j) {
        float t = acca[j] + accb[j] + (float)vd[j] * sl + bias[col + j];
        v[j] = (t >= 0.f) ? t : 0.01f * t;
    }
    if constexpr (std::is_same<OT, bf16>::value) {
        bf16x8 o;
#pragma unroll
        for (int j = 0; j < 8; ++j) o[j] = (bf16)v[j];
        *(bf16x8*)(out + d * 128 + col) = o;
    } else {
        f32x4 o0, o1;
#pragma unroll
        for (int j = 0; j < 4; ++j) { o0[j] = v[j]; o1[j] = v[4 + j]; }
        *(f32x4*)(out + d * 128 + col)     = o0;
        *(f32x4*)(out + d * 128 + col + 4) = o1;
    }
}

// ---------------------------------------------------------------------------
// LP head
// ---------------------------------------------------------------------------
__global__ __launch_bounds__(256) void lp_kernel(
    const float* __restrict__ emb, const int* __restrict__ eli,
    const float* __restrict__ wpost, const float* __restrict__ bpost,
    float* __restrict__ logits, int EL)
{
    const int e = blockIdx.x * 256 + threadIdx.x;
    if (e >= EL) return;
    const long s = eli[e], d = eli[EL + e];
    float acc = 0.f;
#pragma unroll
    for (int c = 0; c < 32; ++c) {
        f32x4 vs = *(const f32x4*)(emb + s * 128 + c * 4);
        f32x4 vd = *(const f32x4*)(emb + d * 128 + c * 4);
        f32x4 w0 = *(const f32x4*)(wpost + c * 4);
        f32x4 w1 = *(const f32x4*)(wpost + 128 + c * 4);
#pragma unroll
        for (int i = 0; i < 4; ++i)
            acc += vs[i] * vd[i] * (w0[i] + w1[i]);
    }
    logits[e] = acc + bpost[0] + bpost[1];
}

// ---------------------------------------------------------------------------
extern "C" void kernel_launch(void* const* d_in, const int* in_sizes, int n_in,
                              void* d_out, int out_size, void* d_ws, size_t ws_size,
                              hipStream_t stream) {
    const float* x      = (const float*)d_in[0];
    const int*   ei     = (const int*)d_in[1];   // [2,E]: row0=src, row1=dst
    const int*   eli    = (const int*)d_in[2];
    const float* prev0  = (const float*)d_in[3];
    const float* prev1  = (const float*)d_in[4];
    const float* w_pre1 = (const float*)d_in[5];
    const float* b_pre1 = (const float*)d_in[6];
    const float* w_pre2 = (const float*)d_in[7];
    const float* b_pre2 = (const float*)d_in[8];
    const float* w_c1   = (const float*)d_in[9];
    const float* b_c1   = (const float*)d_in[10];
    const float* w_c2   = (const float*)d_in[11];
    const float* b_c2   = (const float*)d_in[12];
    const float* w_post = (const float*)d_in[13];
    const float* b_post = (const float*)d_in[14];
    const float* g1_wih = (const float*)d_in[15];
    const float* g1_whh = (const float*)d_in[16];
    const float* g1_bih = (const float*)d_in[17];
    const float* g1_bhh = (const float*)d_in[18];
    const float* g2_wih = (const float*)d_in[19];
    const float* g2_whh = (const float*)d_in[20];
    const float* g2_bih = (const float*)d_in[21];
    const float* g2_bhh = (const float*)d_in[22];

    const int N  = in_sizes[0] / 128;
    const int E  = in_sizes[1] / 2;
    const int EL = in_sizes[2] / 2;
    const long NH = (long)N * 128;

    // outputs (f32)
    float* out    = (float*)d_out;
    float* logits = out;
    float* emb0   = out + EL;
    float* emb1   = emb0 + NH;
    float* emb2   = emb1 + NH;

    // bf16 intermediates living in currently-dead output slots
    bf16* H1b = (bf16*)emb1;   // [N,256] bf16 == emb1 slot exactly
    bf16* H2b = (bf16*)emb2;   // [N,128] bf16 (first half of emb2 slot)
    bf16* h1b = (bf16*)emb2;   // reuses emb2 slot after H2b is dead

    // ---- workspace layout ----
    char* ws = (char*)d_ws;
    size_t p = 0;
    auto alloc = [&](size_t bytes) { size_t o = p; p = (p + bytes + 255) & ~(size_t)255; return o; };
    float* dinv    = (float*)(ws + alloc((size_t)N * 4));
    int*   degi    = (int*)  (ws + alloc((size_t)N * 4));
    int*   inc     = (int*)  (ws + alloc((size_t)N * 4));
    int*   rowptr  = (int*)  (ws + alloc((size_t)N * 4));
    int*   cursor  = (int*)  (ws + alloc((size_t)N * 4));
    int*   bsum    = (int*)  (ws + alloc(4096));
    bf16*  wb      = (bf16*) (ws + alloc((size_t)294912 * 2));
    int*   csr_src = (int*)  (ws + alloc((size_t)E * 4));
    float* csr_nrm = (float*)(ws + alloc((size_t)E * 4));
    const size_t fixed = p;
    bf16*  xwb     = (bf16*)(ws + fixed);

    // xw columns per pass, limited by remaining ws
    int cw = 128;
    while (cw > 16 && fixed + (size_t)N * cw * 2 > ws_size) cw >>= 1;
    const int lg = __builtin_ctz(cw >> 3);
    const int passes = 128 / cw;

    // h2b (conv2 bf16 output) in ws if it fits after a full-width xwb
    const bool big_ws = (cw == 128) &&
        (ws_size >= fixed + (size_t)N * 128 * 2 + (size_t)N * 128 * 2);
    bf16* h2b = big_ws ? (bf16*)(ws + fixed + (size_t)N * 128 * 2) : nullptr;

    // bf16 weight copies (packed into wb)
    bf16* wb_pre1 = wb;                  // 32768
    bf16* wb_pre2 = wb_pre1 + 32768;     // 32768
    bf16* wb_c1   = wb_pre2 + 32768;     // 16384
    bf16* wb_c2   = wb_c1 + 16384;       // 16384
    bf16* wb_g1i  = wb_c2 + 16384;       // 49152
    bf16* wb_g1h  = wb_g1i + 49152;      // 49152
    bf16* wb_g2i  = wb_g1h + 49152;      // 49152
    bf16* wb_g2h  = wb_g2i + 49152;      // 49152

    const int gB = 256;
    const dim3 blk(gB);
    const int grid_rows64 = (N + 63) / 64;
    const int grid_gru    = (N + 63) / 64;    // 4 waves x 16 rows per block
    const int grid_E      = (E + gB - 1) / gB;
    const int grid_N      = (N + gB - 1) / gB;
    const int nb          = (N + 255) / 256;

    cvt_kernel<<<(32768 + 255) / 256, blk, 0, stream>>>(w_pre1, wb_pre1, 32768);
    cvt_kernel<<<(32768 + 255) / 256, blk, 0, stream>>>(w_pre2, wb_pre2, 32768);
    cvt_kernel<<<(16384 + 255) / 256, blk, 0, stream>>>(w_c1, wb_c1, 16384);
    cvt_kernel<<<(16384 + 255) / 256, blk, 0, stream>>>(w_c2, wb_c2, 16384);
    cvt_kernel<<<(49152 + 255) / 256, blk, 0, stream>>>(g1_wih, wb_g1i, 49152);
    cvt_kernel<<<(49152 + 255) / 256, blk, 0, stream>>>(g1_whh, wb_g1h, 49152);
    cvt_kernel<<<(49152 + 255) / 256, blk, 0, stream>>>(g2_wih, wb_g2i, 49152);
    cvt_kernel<<<(49152 + 255) / 256, blk, 0, stream>>>(g2_whh, wb_g2h, 49152);

    // ---- CSR build (once; reused by both convs) ----
    hipMemsetAsync(degi, 0, (size_t)N * 4, stream);
    deg_kernel<<<grid_E, blk, 0, stream>>>(ei + E, degi, E);
    dinv_kernel<<<grid_N, blk, 0, stream>>>(degi, dinv, N);
    scan1_kernel<<<nb, blk, 0, stream>>>(degi, inc, bsum, N);
    scan2_kernel<<<1, 512, 0, stream>>>(bsum, nb);
    scan3_kernel<<<nb, blk, 0, stream>>>(inc, degi, bsum, rowptr, N);
    hipMemsetAsync(cursor, 0, (size_t)N * 4, stream);
    fill_kernel<<<grid_E, blk, 0, stream>>>(ei, ei + E, rowptr, cursor, dinv, csr_src, csr_nrm, E);

    // ---- preprocess: x -> H1b (bf16, emb1 slot) -> H2b (bf16, emb2 slot) ----
    gemm_kernel<128, 256, true, true, float, bf16><<<grid_rows64, blk, 0, stream>>>(x, wb_pre1, b_pre1, H1b, N);
    gemm_kernel<256, 128, true, true, bf16,  bf16><<<grid_rows64, blk, 0, stream>>>(H1b, wb_pre2, b_pre2, H2b, N);

    // GRU1: emb0 = gru(H2b, prev0)
    gru_kernel<bf16><<<grid_gru, blk, 0, stream>>>(H2b, prev0, wb_g1i, wb_g1h, g1_bih, g1_bhh, emb0, N);

    // ---- conv via CSR gather ----
    const int grid_ga = (int)((((long)N << lg) + gB - 1) / gB);
    auto run_gemm = [&](const float* hin, const bf16* wp) {
        switch (cw) {
        case 128: gemm_kernel<128, 128, false, false, float, bf16><<<grid_rows64, blk, 0, stream>>>(hin, wp, nullptr, xwb, N); break;
        case 64:  gemm_kernel<128, 64,  false, false, float, bf16><<<grid_rows64, blk, 0, stream>>>(hin, wp, nullptr, xwb, N); break;
        case 32:  gemm_kernel<128, 32,  false, false, float, bf16><<<grid_rows64, blk, 0, stream>>>(hin, wp, nullptr, xwb, N); break;
        default:  gemm_kernel<128, 16,  false, false, float, bf16><<<grid_rows64, blk, 0, stream>>>(hin, wp, nullptr, xwb, N); break;
        }
    };

    // conv1: emb0 -> xwb -> h1b (bf16, emb2 slot); GRU2 -> emb1 (slot now free)
    for (int ps = 0; ps < passes; ++ps) {
        run_gemm(emb0, wb_c1 + (size_t)(ps * cw) * 128);
        gather_kernel<bf16><<<grid_ga, blk, 0, stream>>>(xwb, rowptr, degi, csr_src, csr_nrm,
                                                         dinv, b_c1, h1b, N, ps * cw, cw, lg);
    }
    gru_kernel<bf16><<<grid_gru, blk, 0, stream>>>(h1b, prev0, wb_g1i, wb_g1h, g1_bih, g1_bhh, emb1, N);

    // conv2: emb1 -> xwb -> h2b (ws) or emb2 f32 (fallback); GRU3 -> emb2
    for (int ps = 0; ps < passes; ++ps) {
        run_gemm(emb1, wb_c2 + (size_t)(ps * cw) * 128);
        if (big_ws)
            gather_kernel<bf16><<<grid_ga, blk, 0, stream>>>(xwb, rowptr, degi, csr_src, csr_nrm,
                                                             dinv, b_c2, h2b, N, ps * cw, cw, lg);
        else
            gather_kernel<float><<<grid_ga, blk, 0, stream>>>(xwb, rowptr, degi, csr_src, csr_nrm,
                                                              dinv, b_c2, emb2, N, ps * cw, cw, lg);
    }
    if (big_ws)
        gru_kernel<bf16><<<grid_gru, blk, 0, stream>>>(h2b, prev1, wb_g2i, wb_g2h, g2_bih, g2_bhh, emb2, N);
    else
        gru_kernel<float><<<grid_gru, blk, 0, stream>>>(emb2, prev1, wb_g2i, wb_g2h, g2_bih, g2_bhh, emb2, N);

    // LP head
    lp_kernel<<<(EL + gB - 1) / gB, blk, 0, stream>>>(emb2, eli, w_post, b_post, logits, EL);
}

// Round 9
// 545.434 us; speedup vs baseline: 9.6620x; 1.0785x over previous
//
#include <hip/hip_runtime.h>
#include <hip/hip_bf16.h>
#include <type_traits>

// ---------------------------------------------------------------------------
// ROLAND GNN forward. Buffers f32; matmuls bf16-MFMA, f32 accum.
// Outputs (concat, f32): logits[EL], emb0[N,128], emb1[N,128], emb2[N,128]
// Round 9: GRU reg-prefetch of next weight tile (T14), fused setup kernels
// (cvt8, scan1+dinv, scan3+cursor-copy), GEMM 2 M-tiles/wave.
// ---------------------------------------------------------------------------

typedef __bf16 bf16;
typedef __bf16 bf16x8 __attribute__((ext_vector_type(8)));
typedef float  f32x4  __attribute__((ext_vector_type(4)));

#define DEV __device__ __forceinline__

DEV f32x4 mfma16(bf16x8 a, bf16x8 b, f32x4 c) {
    return __builtin_amdgcn_mfma_f32_16x16x32_bf16(a, b, c, 0, 0, 0);
}

DEV bf16x8 load_a8(const float* p) {
    f32x4 lo = *(const f32x4*)p;
    f32x4 hi = *(const f32x4*)(p + 4);
    bf16x8 v;
    v[0] = (bf16)lo[0]; v[1] = (bf16)lo[1]; v[2] = (bf16)lo[2]; v[3] = (bf16)lo[3];
    v[4] = (bf16)hi[0]; v[5] = (bf16)hi[1]; v[6] = (bf16)hi[2]; v[7] = (bf16)hi[3];
    return v;
}
DEV bf16x8 load_a8(const bf16* p) { return *(const bf16x8*)p; }

// single fused f32->bf16 conversion of all 8 weight matrices into wb
__global__ void cvt8_kernel(const float* s0, const float* s1, const float* s2, const float* s3,
                            const float* s4, const float* s5, const float* s6, const float* s7,
                            bf16* __restrict__ wb) {
    const int i = blockIdx.x * 256 + threadIdx.x;
    if (i >= 294912) return;
    float v;
    if      (i < 32768)  v = s0[i];
    else if (i < 65536)  v = s1[i - 32768];
    else if (i < 81920)  v = s2[i - 65536];
    else if (i < 98304)  v = s3[i - 81920];
    else if (i < 147456) v = s4[i - 98304];
    else if (i < 196608) v = s5[i - 147456];
    else if (i < 245760) v = s6[i - 196608];
    else                 v = s7[i - 245760];
    wb[i] = (bf16)v;
}

// ---------------------------------------------------------------------------
// GEMM: C[M,Co] = act(A[M,Ci] @ W[Co,Ci]^T + bias). A f32|bf16, W bf16.
// 2 M-tiles per wave (128-row blocks): each W fragment feeds 2 MFMAs.
// MFMA 16x16x32 bf16; C/D layout (m89): col=lane&15, row=4*(lane>>4)+j.
// ---------------------------------------------------------------------------
template<int Ci, int Co, bool ACT, bool BIAS, typename AT, typename OT>
__global__ __launch_bounds__(256) void gemm_kernel(
    const AT* __restrict__ A, const bf16* __restrict__ W,
    const float* __restrict__ bias, OT* __restrict__ C, int M)
{
    const int tid  = threadIdx.x;
    const int lane = tid & 63, w = tid >> 6;
    const int lr   = lane & 15, ko = lane >> 4;
    const int rbase = blockIdx.x * 128 + w * 32;

    constexpr int KC = Ci / 32;
    constexpr int NT = Co / 16;

    bf16x8 a[2][KC];
#pragma unroll
    for (int m = 0; m < 2; ++m) {
        long arow = rbase + m * 16 + lr; if (arow > M - 1) arow = M - 1;  // clamped rows never stored
#pragma unroll
        for (int kc = 0; kc < KC; ++kc)
            a[m][kc] = load_a8(A + arow * Ci + kc * 32 + ko * 8);
    }

#pragma unroll
    for (int t = 0; t < NT; ++t) {
        f32x4 acc0 = {0.f, 0.f, 0.f, 0.f};
        f32x4 acc1 = {0.f, 0.f, 0.f, 0.f};
        const bf16* wp = W + (long)(t * 16 + lr) * Ci + ko * 8;
#pragma unroll
        for (int kc = 0; kc < KC; ++kc) {
            bf16x8 wf = *(const bf16x8*)(wp + kc * 32);
            acc0 = mfma16(a[0][kc], wf, acc0);
            acc1 = mfma16(a[1][kc], wf, acc1);
        }

        const int col = t * 16 + lr;
        float bv = 0.f;
        if (BIAS) bv = bias[col];
#pragma unroll
        for (int j = 0; j < 4; ++j) {
            const int r0 = rbase + ko * 4 + j;
            if (r0 < M) {
                float v = acc0[j] + bv;
                if (ACT) v = (v >= 0.f) ? v : 0.01f * v;
                C[(long)r0 * Co + col] = (OT)v;
            }
            const int r1 = rbase + 16 + ko * 4 + j;
            if (r1 < M) {
                float v = acc1[j] + bv;
                if (ACT) v = (v >= 0.f) ? v : 0.01f * v;
                C[(long)r1 * Co + col] = (OT)v;
            }
        }
    }
}

// ---------------------------------------------------------------------------
// GRUCell, 64-row blocks (4 waves x 16 rows), LDS weight tiles with
// register prefetch of the NEXT tile (stage latency hides under compute).
// Safe for out == x (f32 path): all A-frag reads precede the first barrier.
// ---------------------------------------------------------------------------
template<typename XT>
__global__ __launch_bounds__(256) void gru_kernel(
    const XT* x, const float* __restrict__ hp,
    const bf16* __restrict__ wih, const bf16* __restrict__ whh,
    const float* __restrict__ bih, const float* __restrict__ bhh,
    float* out, int N)
{
    __shared__ bf16 Lw[6][16][128];   // 24 KB

    const int tid  = threadIdx.x;
    const int lane = tid & 63, w = tid >> 6;
    const int lr   = lane & 15, ko = lane >> 4;
    const long rbase = (long)blockIdx.x * 64 + w * 16;

    long arow = rbase + lr; if (arow > N - 1) arow = N - 1;
    bf16x8 ax[4], ah[4];
#pragma unroll
    for (int kc = 0; kc < 4; ++kc) {
        ax[kc] = load_a8(x  + arow * 128 + kc * 32 + ko * 8);
        ah[kc] = load_a8(hp + arow * 128 + kc * 32 + ko * 8);
    }

    bf16x8 pre[6];
    auto LDW = [&](int tc) {
#pragma unroll
        for (int i = 0; i < 6; ++i) {
            const int ch  = tid + 256 * i;
            const int g   = ch >> 8, rem = ch & 255;
            const int row = rem >> 4, cc = rem & 15;
            const int scc = cc ^ (row & 7);
            pre[i] = *(const bf16x8*)((g < 3 ? wih : whh)
                + (long)(((g % 3) * 128 + tc * 16 + row) * 128 + scc * 8));
        }
    };
    LDW(0);

    for (int tc = 0; tc < 8; ++tc) {
        __syncthreads();   // previous tile's LDS reads complete
#pragma unroll
        for (int i = 0; i < 6; ++i) {
            const int ch  = tid + 256 * i;
            const int g   = ch >> 8, rem = ch & 255;
            const int row = rem >> 4, cc = rem & 15;
            *(bf16x8*)(&Lw[g][row][cc * 8]) = pre[i];
        }
        __syncthreads();
        if (tc < 7) LDW(tc + 1);   // prefetch next tile; latency hides under compute

        const int col = tc * 16 + lr;
        const float br = bih[col]       + bhh[col];
        const float bz = bih[128 + col] + bhh[128 + col];
        const float bi = bih[256 + col];
        const float bh = bhh[256 + col];

        f32x4 ar = {0.f, 0.f, 0.f, 0.f};
        f32x4 az = {0.f, 0.f, 0.f, 0.f};
        f32x4 ai = {0.f, 0.f, 0.f, 0.f};
        f32x4 ag = {0.f, 0.f, 0.f, 0.f};
#pragma unroll
        for (int kc = 0; kc < 4; ++kc) {
            const int cc = (kc * 4 + ko) ^ (lr & 7);
            bf16x8 wr_i = *(const bf16x8*)(&Lw[0][lr][cc * 8]);
            bf16x8 wz_i = *(const bf16x8*)(&Lw[1][lr][cc * 8]);
            bf16x8 wn_i = *(const bf16x8*)(&Lw[2][lr][cc * 8]);
            bf16x8 wr_h = *(const bf16x8*)(&Lw[3][lr][cc * 8]);
            bf16x8 wz_h = *(const bf16x8*)(&Lw[4][lr][cc * 8]);
            bf16x8 wn_h = *(const bf16x8*)(&Lw[5][lr][cc * 8]);
            ar = mfma16(ax[kc], wr_i, ar);
            ar = mfma16(ah[kc], wr_h, ar);
            az = mfma16(ax[kc], wz_i, az);
            az = mfma16(ah[kc], wz_h, az);
            ai = mfma16(ax[kc], wn_i, ai);
            ag = mfma16(ah[kc], wn_h, ag);
        }
#pragma unroll
        for (int j = 0; j < 4; ++j) {
            const long row = rbase + ko * 4 + j;
            if (row < N) {
                const float r = 1.f / (1.f + __expf(-(ar[j] + br)));
                const float z = 1.f / (1.f + __expf(-(az[j] + bz)));
                const float pre_ = (ai[j] + bi) + r * (ag[j] + bh);
                const float n = 1.f - 2.f / (1.f + __expf(2.f * pre_));
                out[row * 128 + col] = (1.f - z) * n + z * hp[row * 128 + col];
            }
        }
    }
}

// ---------------------------------------------------------------------------
// CSR build
// ---------------------------------------------------------------------------
__global__ void deg_kernel(const int* __restrict__ dst, int* degi, int E) {
    const int e = blockIdx.x * 256 + threadIdx.x;
    if (e < E) atomicAdd(&degi[dst[e]], 1);
}

// block inclusive scan + dinv (fused)
__global__ void scan1_kernel(const int* __restrict__ degi, int* __restrict__ inc,
                             int* __restrict__ bsum, float* __restrict__ dinv, int N) {
    __shared__ int s[256];
    const int i = blockIdx.x * 256 + threadIdx.x;
    const int d = (i < N) ? degi[i] : 0;
    if (i < N) dinv[i] = rsqrtf((float)d + 1.0f);   // +1 self loop
    s[threadIdx.x] = d;
    __syncthreads();
#pragma unroll
    for (int off = 1; off < 256; off <<= 1) {
        int t = (threadIdx.x >= off) ? s[threadIdx.x - off] : 0;
        __syncthreads();
        s[threadIdx.x] += t;
        __syncthreads();
    }
    if (i < N) inc[i] = s[threadIdx.x];
    if (threadIdx.x == 255) bsum[blockIdx.x] = s[255];
}

__global__ void scan2_kernel(int* bsum, int nb) {
    __shared__ int s[512];
    __shared__ int carry;
    if (threadIdx.x == 0) carry = 0;
    __syncthreads();
    for (int base = 0; base < nb; base += 512) {
        const int i = base + threadIdx.x;
        s[threadIdx.x] = (i < nb) ? bsum[i] : 0;
        __syncthreads();
#pragma unroll
        for (int off = 1; off < 512; off <<= 1) {
            int t = (threadIdx.x >= off) ? s[threadIdx.x - off] : 0;
            __syncthreads();
            s[threadIdx.x] += t;
            __syncthreads();
        }
        const int c = carry;
        if (i < nb) bsum[i] = s[threadIdx.x] + c;
        __syncthreads();
        if (threadIdx.x == 511) carry = c + s[511];
        __syncthreads();
    }
}

// rowptr + a mutable copy (rp2) that fill bumps atomically (no memset needed)
__global__ void scan3_kernel(const int* __restrict__ inc, const int* __restrict__ degi,
                             const int* __restrict__ bsum, int* __restrict__ rowptr,
                             int* __restrict__ rp2, int N) {
    const int i = blockIdx.x * 256 + threadIdx.x;
    if (i >= N) return;
    const int prev = (blockIdx.x > 0) ? bsum[blockIdx.x - 1] : 0;
    const int rp = prev + inc[i] - degi[i];   // exclusive prefix
    rowptr[i] = rp;
    rp2[i]    = rp;
}

__global__ void fill_kernel(const int* __restrict__ src, const int* __restrict__ dst,
                            int* rp2, const float* __restrict__ dinv,
                            int* __restrict__ csr_src, float* __restrict__ csr_norm, int E) {
    const int e = blockIdx.x * 256 + threadIdx.x;
    if (e >= E) return;
    const int s = src[e], d = dst[e];
    const int pos = atomicAdd(&rp2[d], 1);
    csr_src[pos]  = s;
    csr_norm[pos] = dinv[s] * dinv[d];
}

// ---------------------------------------------------------------------------
// Fused gather + finalize, dual-chain edge pipeline:
// out[d, cols] = leaky(sum_in xwb[s]*nm + xwb[d]*di^2 + b)
// ---------------------------------------------------------------------------
template<typename OT>
__global__ __launch_bounds__(256) void gather_kernel(
    const bf16* __restrict__ xwb,            // [N, cw] bf16
    const int* __restrict__ rowptr, const int* __restrict__ degi,
    const int* __restrict__ csr_src, const float* __restrict__ csr_norm,
    const float* __restrict__ dinv, const float* __restrict__ bias,
    OT* __restrict__ out, int N, int colbase, int cw, int lg)
{
    const long tid = (long)blockIdx.x * 256 + threadIdx.x;
    const long d = tid >> lg;
    const int  c = (int)(tid & ((1 << lg) - 1));
    if (d >= N) return;

    const int start = rowptr[d];
    const int deg   = degi[d];
    const int h     = deg >> 1;
    const bf16* xb  = xwb + c * 8;

    float acca[8] = {0.f, 0.f, 0.f, 0.f, 0.f, 0.f, 0.f, 0.f};
    float accb[8] = {0.f, 0.f, 0.f, 0.f, 0.f, 0.f, 0.f, 0.f};
    for (int k = 0; k < h; ++k) {
        const int   sa = csr_src[start + k];
        const int   sb = csr_src[start + h + k];
        const float na = csr_norm[start + k];
        const float nb_ = csr_norm[start + h + k];
        bf16x8 va = *(const bf16x8*)(xb + (long)sa * cw);
        bf16x8 vb = *(const bf16x8*)(xb + (long)sb * cw);
#pragma unroll
        for (int j = 0; j < 8; ++j) {
            acca[j] += (float)va[j] * na;
            accb[j] += (float)vb[j] * nb_;
        }
    }
    if (deg & 1) {
        const int   s  = csr_src[start + deg - 1];
        const float nm = csr_norm[start + deg - 1];
        bf16x8 v = *(const bf16x8*)(xb + (long)s * cw);
#pragma unroll
        for (int j = 0; j < 8; ++j) acca[j] += (float)v[j] * nm;
    }

    const float di = dinv[d], sl = di * di;
    bf16x8 vd = *(const bf16x8*)(xb + d * cw);
    const int col = colbase + c * 8;
    float v[8];
#pragma unroll
    for (int j = 0; j < 8; ++j) {
        float t = acca[j] + accb[j] + (float)vd[j] * sl + bias[col + j];
        v[j] = (t >= 0.f) ? t : 0.01f * t;
    }
    if constexpr (std::is_same<OT, bf16>::value) {
        bf16x8 o;
#pragma unroll
        for (int j = 0; j < 8; ++j) o[j] = (bf16)v[j];
        *(bf16x8*)(out + d * 128 + col) = o;
    } else {
        f32x4 o0, o1;
#pragma unroll
        for (int j = 0; j < 4; ++j) { o0[j] = v[j]; o1[j] = v[4 + j]; }
        *(f32x4*)(out + d * 128 + col)     = o0;
        *(f32x4*)(out + d * 128 + col + 4) = o1;
    }
}

// ---------------------------------------------------------------------------
// LP head
// ---------------------------------------------------------------------------
__global__ __launch_bounds__(256) void lp_kernel(
    const float* __restrict__ emb, const int* __restrict__ eli,
    const float* __restrict__ wpost, const float* __restrict__ bpost,
    float* __restrict__ logits, int EL)
{
    const int e = blockIdx.x * 256 + threadIdx.x;
    if (e >= EL) return;
    const long s = eli[e], d = eli[EL + e];
    float acc = 0.f;
#pragma unroll
    for (int c = 0; c < 32; ++c) {
        f32x4 vs = *(const f32x4*)(emb + s * 128 + c * 4);
        f32x4 vd = *(const f32x4*)(emb + d * 128 + c * 4);
        f32x4 w0 = *(const f32x4*)(wpost + c * 4);
        f32x4 w1 = *(const f32x4*)(wpost + 128 + c * 4);
#pragma unroll
        for (int i = 0; i < 4; ++i)
            acc += vs[i] * vd[i] * (w0[i] + w1[i]);
    }
    logits[e] = acc + bpost[0] + bpost[1];
}

// ---------------------------------------------------------------------------
extern "C" void kernel_launch(void* const* d_in, const int* in_sizes, int n_in,
                              void* d_out, int out_size, void* d_ws, size_t ws_size,
                              hipStream_t stream) {
    const float* x      = (const float*)d_in[0];
    const int*   ei     = (const int*)d_in[1];   // [2,E]: row0=src, row1=dst
    const int*   eli    = (const int*)d_in[2];
    const float* prev0  = (const float*)d_in[3];
    const float* prev1  = (const float*)d_in[4];
    const float* w_pre1 = (const float*)d_in[5];
    const float* b_pre1 = (const float*)d_in[6];
    const float* w_pre2 = (const float*)d_in[7];
    const float* b_pre2 = (const float*)d_in[8];
    const float* w_c1   = (const float*)d_in[9];
    const float* b_c1   = (const float*)d_in[10];
    const float* w_c2   = (const float*)d_in[11];
    const float* b_c2   = (const float*)d_in[12];
    const float* w_post = (const float*)d_in[13];
    const float* b_post = (const float*)d_in[14];
    const float* g1_wih = (const float*)d_in[15];
    const float* g1_whh = (const float*)d_in[16];
    const float* g1_bih = (const float*)d_in[17];
    const float* g1_bhh = (const float*)d_in[18];
    const float* g2_wih = (const float*)d_in[19];
    const float* g2_whh = (const float*)d_in[20];
    const float* g2_bih = (const float*)d_in[21];
    const float* g2_bhh = (const float*)d_in[22];

    const int N  = in_sizes[0] / 128;
    const int E  = in_sizes[1] / 2;
    const int EL = in_sizes[2] / 2;
    const long NH = (long)N * 128;

    // outputs (f32)
    float* out    = (float*)d_out;
    float* logits = out;
    float* emb0   = out + EL;
    float* emb1   = emb0 + NH;
    float* emb2   = emb1 + NH;

    // bf16 intermediates living in currently-dead output slots
    bf16* H1b = (bf16*)emb1;   // [N,256] bf16 == emb1 slot exactly
    bf16* H2b = (bf16*)emb2;   // [N,128] bf16 (first half of emb2 slot)
    bf16* h1b = (bf16*)emb2;   // reuses emb2 slot after H2b is dead

    // ---- workspace layout ----
    char* ws = (char*)d_ws;
    size_t p = 0;
    auto alloc = [&](size_t bytes) { size_t o = p; p = (p + bytes + 255) & ~(size_t)255; return o; };
    float* dinv    = (float*)(ws + alloc((size_t)N * 4));
    int*   degi    = (int*)  (ws + alloc((size_t)N * 4));
    int*   inc     = (int*)  (ws + alloc((size_t)N * 4));
    int*   rowptr  = (int*)  (ws + alloc((size_t)N * 4));
    int*   rp2     = (int*)  (ws + alloc((size_t)N * 4));
    int*   bsum    = (int*)  (ws + alloc(4096));
    bf16*  wb      = (bf16*) (ws + alloc((size_t)294912 * 2));
    int*   csr_src = (int*)  (ws + alloc((size_t)E * 4));
    float* csr_nrm = (float*)(ws + alloc((size_t)E * 4));
    const size_t fixed = p;
    bf16*  xwb     = (bf16*)(ws + fixed);

    // xw columns per pass, limited by remaining ws
    int cw = 128;
    while (cw > 16 && fixed + (size_t)N * cw * 2 > ws_size) cw >>= 1;
    const int lg = __builtin_ctz(cw >> 3);
    const int passes = 128 / cw;

    // h2b (conv2 bf16 output) in ws if it fits after a full-width xwb
    const bool big_ws = (cw == 128) &&
        (ws_size >= fixed + (size_t)N * 128 * 2 + (size_t)N * 128 * 2);
    bf16* h2b = big_ws ? (bf16*)(ws + fixed + (size_t)N * 128 * 2) : nullptr;

    // bf16 weight copies (packed into wb, order matches cvt8)
    bf16* wb_pre1 = wb;                  // 32768
    bf16* wb_pre2 = wb_pre1 + 32768;     // 32768
    bf16* wb_c1   = wb_pre2 + 32768;     // 16384
    bf16* wb_c2   = wb_c1 + 16384;       // 16384
    bf16* wb_g1i  = wb_c2 + 16384;       // 49152
    bf16* wb_g1h  = wb_g1i + 49152;      // 49152
    bf16* wb_g2i  = wb_g1h + 49152;      // 49152
    bf16* wb_g2h  = wb_g2i + 49152;      // 49152

    const int gB = 256;
    const dim3 blk(gB);
    const int grid_rows128 = (N + 127) / 128;  // gemm: 128 rows/block
    const int grid_gru     = (N + 63) / 64;    // gru: 64 rows/block
    const int grid_E       = (E + gB - 1) / gB;
    const int nb           = (N + 255) / 256;

    cvt8_kernel<<<(294912 + 255) / 256, blk, 0, stream>>>(
        w_pre1, w_pre2, w_c1, w_c2, g1_wih, g1_whh, g2_wih, g2_whh, wb);

    // ---- CSR build (once; reused by both convs) ----
    hipMemsetAsync(degi, 0, (size_t)N * 4, stream);
    deg_kernel<<<grid_E, blk, 0, stream>>>(ei + E, degi, E);
    scan1_kernel<<<nb, blk, 0, stream>>>(degi, inc, bsum, dinv, N);
    scan2_kernel<<<1, 512, 0, stream>>>(bsum, nb);
    scan3_kernel<<<nb, blk, 0, stream>>>(inc, degi, bsum, rowptr, rp2, N);
    fill_kernel<<<grid_E, blk, 0, stream>>>(ei, ei + E, rp2, dinv, csr_src, csr_nrm, E);

    // ---- preprocess: x -> H1b (bf16, emb1 slot) -> H2b (bf16, emb2 slot) ----
    gemm_kernel<128, 256, true, true, float, bf16><<<grid_rows128, blk, 0, stream>>>(x, wb_pre1, b_pre1, H1b, N);
    gemm_kernel<256, 128, true, true, bf16,  bf16><<<grid_rows128, blk, 0, stream>>>(H1b, wb_pre2, b_pre2, H2b, N);

    // GRU1: emb0 = gru(H2b, prev0)
    gru_kernel<bf16><<<grid_gru, blk, 0, stream>>>(H2b, prev0, wb_g1i, wb_g1h, g1_bih, g1_bhh, emb0, N);

    // ---- conv via CSR gather ----
    const int grid_ga = (int)((((long)N << lg) + gB - 1) / gB);
    auto run_gemm = [&](const float* hin, const bf16* wp) {
        switch (cw) {
        case 128: gemm_kernel<128, 128, false, false, float, bf16><<<grid_rows128, blk, 0, stream>>>(hin, wp, nullptr, xwb, N); break;
        case 64:  gemm_kernel<128, 64,  false, false, float, bf16><<<grid_rows128, blk, 0, stream>>>(hin, wp, nullptr, xwb, N); break;
        case 32:  gemm_kernel<128, 32,  false, false, float, bf16><<<grid_rows128, blk, 0, stream>>>(hin, wp, nullptr, xwb, N); break;
        default:  gemm_kernel<128, 16,  false, false, float, bf16><<<grid_rows128, blk, 0, stream>>>(hin, wp, nullptr, xwb, N); break;
        }
    };

    // conv1: emb0 -> xwb -> h1b (bf16, emb2 slot); GRU2 -> emb1 (slot now free)
    for (int ps = 0; ps < passes; ++ps) {
        run_gemm(emb0, wb_c1 + (size_t)(ps * cw) * 128);
        gather_kernel<bf16><<<grid_ga, blk, 0, stream>>>(xwb, rowptr, degi, csr_src, csr_nrm,
                                                         dinv, b_c1, h1b, N, ps * cw, cw, lg);
    }
    gru_kernel<bf16><<<grid_gru, blk, 0, stream>>>(h1b, prev0, wb_g1i, wb_g1h, g1_bih, g1_bhh, emb1, N);

    // conv2: emb1 -> xwb -> h2b (ws) or emb2 f32 (fallback); GRU3 -> emb2
    for (int ps = 0; ps < passes; ++ps) {
        run_gemm(emb1, wb_c2 + (size_t)(ps * cw) * 128);
        if (big_ws)
            gather_kernel<bf16><<<grid_ga, blk, 0, stream>>>(xwb, rowptr, degi, csr_src, csr_nrm,
                                                             dinv, b_c2, h2b, N, ps * cw, cw, lg);
        else
            gather_kernel<float><<<grid_ga, blk, 0, stream>>>(xwb, rowptr, degi, csr_src, csr_nrm,
                                                              dinv, b_c2, emb2, N, ps * cw, cw, lg);
    }
    if (big_ws)
        gru_kernel<bf16><<<grid_gru, blk, 0, stream>>>(h2b, prev1, wb_g2i, wb_g2h, g2_bih, g2_bhh, emb2, N);
    else
        gru_kernel<float><<<grid_gru, blk, 0, stream>>>(emb2, prev1, wb_g2i, wb_g2h, g2_bih, g2_bhh, emb2, N);

    // LP head
    lp_kernel<<<(EL + gB - 1) / gB, blk, 0, stream>>>(emb2, eli, w_post, b_post, logits, EL);
}